// Round 2
// baseline (2042.387 us; speedup 1.0000x reference)
//
#include <hip/hip_runtime.h>

#define DIM 1536
#define IMG 1024
#define TXT 256
#define SEQ 1280
#define NH 24
#define HD 64

typedef __attribute__((ext_vector_type(8))) short short8;
typedef __attribute__((ext_vector_type(4))) float f32x4;

__device__ __forceinline__ float bf2f(ushort u) {
    union { unsigned int i; float f; } v; v.i = ((unsigned int)u) << 16; return v.f;
}
__device__ __forceinline__ ushort f2bf(float f) {
    union { unsigned int i; float f; } v; v.f = f;
    unsigned int u = v.i;
    u += 0x7fffu + ((u >> 16) & 1u);
    return (ushort)(u >> 16);
}

// ---------------------------------------------------------------------------
// Input-dtype detector. Reads first 4096 ushorts of hidden_states (safe under
// bf16: buffer is 2*1.57M bytes; under fp32: 4x). If the underlying data is
// fp32, even ushort indices are float mantissa low-halves -> uniform bits ->
// ~25% have bf16-exponent-field >= 0xC0. True bf16 N(0,1) data: zero such.
// flag = 1 -> inputs/outputs are fp32 ; flag = 0 -> bf16.
// ---------------------------------------------------------------------------
__global__ __launch_bounds__(256) void detect_dtype(const void* __restrict__ p,
                                                    int* __restrict__ flag)
{
    __shared__ int cnt;
    if (threadIdx.x == 0) cnt = 0;
    __syncthreads();
    const ushort* u = (const ushort*)p;
    int local = 0;
    for (int i = threadIdx.x; i < 2048; i += 256) {
        ushort v = u[2 * i];
        int e = (v >> 7) & 0xFF;
        if (e >= 0xC0) local++;
    }
    atomicAdd(&cnt, local);
    __syncthreads();
    if (threadIdx.x == 0) flag[0] = (cnt > 16) ? 1 : 0;
}

// ---------------------------------------------------------------------------
// GEMM 1: Y(f32,ws) = X @ W + bias ; X,W,bias are inputs (bf16 or fp32 per
// flag). 64x64 tile, BK=32, 4 waves, 2x2 MFMA 16x16x32 each.
// ---------------------------------------------------------------------------
__global__ __launch_bounds__(256) void gemm_in_f32out(
    const void* __restrict__ X, const void* __restrict__ W,
    const void* __restrict__ bias, float* __restrict__ Y,
    const int* __restrict__ dflag)
{
    __shared__ __align__(16) ushort As[64][40];
    __shared__ __align__(16) ushort Bs[64][40];   // [n][k]
    const int dt = dflag[0];
    const int n0 = blockIdx.x * 64, m0 = blockIdx.y * 64;
    const int t = threadIdx.x;
    const int wave = t >> 6, lane = t & 63;
    const int quad = lane >> 4, l16 = lane & 15;
    const int wm = (wave >> 1) * 32, wn = (wave & 1) * 32;

    f32x4 acc[2][2];
#pragma unroll
    for (int i = 0; i < 2; ++i)
#pragma unroll
        for (int j = 0; j < 2; ++j) acc[i][j] = (f32x4)(0.0f);

    const int ar = t >> 2, ac = (t & 3) << 3;     // A stage: 64 rows x 32 k
    const int bk = t >> 3, bn = (t & 7) << 3;     // B stage: 32 k x 64 n

    for (int k0 = 0; k0 < DIM; k0 += 32) {
        const size_t xoff = (size_t)(m0 + ar) * DIM + k0 + ac;
        if (dt) {
            const float* xp = (const float*)X + xoff;
            float4 a = *(const float4*)xp;
            float4 b = *(const float4*)(xp + 4);
            ushort tmp[8] = {f2bf(a.x), f2bf(a.y), f2bf(a.z), f2bf(a.w),
                             f2bf(b.x), f2bf(b.y), f2bf(b.z), f2bf(b.w)};
            *(uint4*)&As[ar][ac] = *(uint4*)tmp;
        } else {
            *(uint4*)&As[ar][ac] = *(const uint4*)((const ushort*)X + xoff);
        }
        const size_t woff = (size_t)(k0 + bk) * DIM + n0 + bn;
        ushort tmp[8];
        if (dt) {
            const float* wp = (const float*)W + woff;
            float4 a = *(const float4*)wp;
            float4 b = *(const float4*)(wp + 4);
            tmp[0] = f2bf(a.x); tmp[1] = f2bf(a.y); tmp[2] = f2bf(a.z); tmp[3] = f2bf(a.w);
            tmp[4] = f2bf(b.x); tmp[5] = f2bf(b.y); tmp[6] = f2bf(b.z); tmp[7] = f2bf(b.w);
        } else {
            *(uint4*)tmp = *(const uint4*)((const ushort*)W + woff);
        }
#pragma unroll
        for (int j = 0; j < 8; ++j) Bs[bn + j][bk] = tmp[j];
        __syncthreads();

        short8 a[2], b[2];
#pragma unroll
        for (int i = 0; i < 2; ++i) a[i] = *(const short8*)&As[wm + i * 16 + l16][quad * 8];
#pragma unroll
        for (int i = 0; i < 2; ++i) b[i] = *(const short8*)&Bs[wn + i * 16 + l16][quad * 8];
#pragma unroll
        for (int i = 0; i < 2; ++i)
#pragma unroll
            for (int j = 0; j < 2; ++j)
                acc[i][j] = __builtin_amdgcn_mfma_f32_16x16x32_bf16(a[i], b[j], acc[i][j], 0, 0, 0);
        __syncthreads();
    }

#pragma unroll
    for (int i = 0; i < 2; ++i)
#pragma unroll
        for (int j = 0; j < 2; ++j) {
            const int col = n0 + wn + j * 16 + l16;
            const float bv = dt ? ((const float*)bias)[col] : bf2f(((const ushort*)bias)[col]);
#pragma unroll
            for (int r = 0; r < 4; ++r) {
                const int row = m0 + wm + i * 16 + quad * 4 + r;
                Y[(size_t)row * DIM + col] = acc[i][j][r] + bv;
            }
        }
}

// ---------------------------------------------------------------------------
// GEMM 2: out(dtype per flag) = X(f32 ws, hi/lo split) @ W + bias.
// ---------------------------------------------------------------------------
__global__ __launch_bounds__(256) void gemm_f32split_out(
    const float* __restrict__ X, const void* __restrict__ W,
    const void* __restrict__ bias, void* __restrict__ Yb, long elem_off,
    const int* __restrict__ dflag)
{
    __shared__ __align__(16) ushort Ah[64][40];
    __shared__ __align__(16) ushort Al[64][40];
    __shared__ __align__(16) ushort Bs[64][40];
    const int dt = dflag[0];
    const int n0 = blockIdx.x * 64, m0 = blockIdx.y * 64;
    const int t = threadIdx.x;
    const int wave = t >> 6, lane = t & 63;
    const int quad = lane >> 4, l16 = lane & 15;
    const int wm = (wave >> 1) * 32, wn = (wave & 1) * 32;

    f32x4 acc[2][2];
#pragma unroll
    for (int i = 0; i < 2; ++i)
#pragma unroll
        for (int j = 0; j < 2; ++j) acc[i][j] = (f32x4)(0.0f);

    const int ar = t >> 2, ac = (t & 3) << 3;
    const int bk = t >> 3, bn = (t & 7) << 3;

    for (int k0 = 0; k0 < DIM; k0 += 32) {
        const float* xp = X + (size_t)(m0 + ar) * DIM + k0 + ac;
        float4 x0 = *(const float4*)xp;
        float4 x1 = *(const float4*)(xp + 4);
        float xs[8] = {x0.x, x0.y, x0.z, x0.w, x1.x, x1.y, x1.z, x1.w};
        ushort hi[8], lo[8];
#pragma unroll
        for (int j = 0; j < 8; ++j) {
            hi[j] = f2bf(xs[j]);
            lo[j] = f2bf(xs[j] - bf2f(hi[j]));
        }
        *(uint4*)&Ah[ar][ac] = *(uint4*)hi;
        *(uint4*)&Al[ar][ac] = *(uint4*)lo;
        const size_t woff = (size_t)(k0 + bk) * DIM + n0 + bn;
        ushort tmp[8];
        if (dt) {
            const float* wp = (const float*)W + woff;
            float4 a = *(const float4*)wp;
            float4 b = *(const float4*)(wp + 4);
            tmp[0] = f2bf(a.x); tmp[1] = f2bf(a.y); tmp[2] = f2bf(a.z); tmp[3] = f2bf(a.w);
            tmp[4] = f2bf(b.x); tmp[5] = f2bf(b.y); tmp[6] = f2bf(b.z); tmp[7] = f2bf(b.w);
        } else {
            *(uint4*)tmp = *(const uint4*)((const ushort*)W + woff);
        }
#pragma unroll
        for (int j = 0; j < 8; ++j) Bs[bn + j][bk] = tmp[j];
        __syncthreads();

        short8 ah[2], al[2], b[2];
#pragma unroll
        for (int i = 0; i < 2; ++i) ah[i] = *(const short8*)&Ah[wm + i * 16 + l16][quad * 8];
#pragma unroll
        for (int i = 0; i < 2; ++i) al[i] = *(const short8*)&Al[wm + i * 16 + l16][quad * 8];
#pragma unroll
        for (int i = 0; i < 2; ++i) b[i] = *(const short8*)&Bs[wn + i * 16 + l16][quad * 8];
#pragma unroll
        for (int i = 0; i < 2; ++i)
#pragma unroll
            for (int j = 0; j < 2; ++j) {
                acc[i][j] = __builtin_amdgcn_mfma_f32_16x16x32_bf16(ah[i], b[j], acc[i][j], 0, 0, 0);
                acc[i][j] = __builtin_amdgcn_mfma_f32_16x16x32_bf16(al[i], b[j], acc[i][j], 0, 0, 0);
            }
        __syncthreads();
    }

#pragma unroll
    for (int i = 0; i < 2; ++i)
#pragma unroll
        for (int j = 0; j < 2; ++j) {
            const int col = n0 + wn + j * 16 + l16;
            const float bv = dt ? ((const float*)bias)[col] : bf2f(((const ushort*)bias)[col]);
#pragma unroll
            for (int r = 0; r < 4; ++r) {
                const int row = m0 + wm + i * 16 + quad * 4 + r;
                const size_t o = (size_t)elem_off + (size_t)row * DIM + col;
                const float val = acc[i][j][r] + bv;
                if (dt) ((float*)Yb)[o] = val;
                else    ((ushort*)Yb)[o] = f2bf(val);
            }
        }
}

// ---------------------------------------------------------------------------
// RoPE kernels. pe flat layout: s*128 + i*4 + {cos,-sin,sin,cos}.
// ---------------------------------------------------------------------------
__device__ __forceinline__ void pe_load(const void* pe, int dt, size_t off,
                                        float& c00, float& c01, float& c10, float& c11)
{
    if (dt) {
        float4 pv = *(const float4*)((const float*)pe + off);
        c00 = pv.x; c01 = pv.y; c10 = pv.z; c11 = pv.w;
    } else {
        const ushort* pp = (const ushort*)pe + off;
        c00 = bf2f(pp[0]); c01 = bf2f(pp[1]); c10 = bf2f(pp[2]); c11 = bf2f(pp[3]);
    }
}

__global__ __launch_bounds__(256) void rope_f32_inplace(
    float* __restrict__ buf, const void* __restrict__ pe,
    const int* __restrict__ dflag, int S)
{
    const int dt = dflag[0];
    int idx = blockIdx.x * 256 + threadIdx.x;
    if (idx >= S * 768) return;
    int s = idx / 768, p = idx - s * 768;
    int col = p << 1, i = p & 31;
    float* bp = buf + (size_t)s * DIM + col;
    float x0 = bp[0], x1 = bp[1];
    float c00, c01, c10, c11;
    pe_load(pe, dt, (size_t)s * 128 + i * 4, c00, c01, c10, c11);
    bp[0] = c00 * x0 + c01 * x1;
    bp[1] = c10 * x0 + c11 * x1;
}

__global__ __launch_bounds__(256) void rope_in_to_f32(
    const void* __restrict__ src, const void* __restrict__ pe,
    float* __restrict__ dst, const int* __restrict__ dflag, int S)
{
    const int dt = dflag[0];
    int idx = blockIdx.x * 256 + threadIdx.x;
    if (idx >= S * 768) return;
    int s = idx / 768, p = idx - s * 768;
    int col = p << 1, i = p & 31;
    float x0, x1;
    if (dt) {
        float2 xv = *(const float2*)((const float*)src + (size_t)s * DIM + col);
        x0 = xv.x; x1 = xv.y;
    } else {
        const ushort* sp = (const ushort*)src + (size_t)s * DIM + col;
        x0 = bf2f(sp[0]); x1 = bf2f(sp[1]);
    }
    float c00, c01, c10, c11;
    pe_load(pe, dt, (size_t)s * 128 + i * 4, c00, c01, c10, c11);
    float* dp = dst + (size_t)s * DIM + col;
    dp[0] = c00 * x0 + c01 * x1;
    dp[1] = c10 * x0 + c11 * x1;
}

// ---------------------------------------------------------------------------
// Attention, fp32, Skv = 1280. One WG (256 thr) = 8 q rows of one head.
// ---------------------------------------------------------------------------
__global__ __launch_bounds__(256) void attn_f32(
    const float* __restrict__ Q, const float* __restrict__ K,
    const float* __restrict__ V, float* __restrict__ O)
{
    const int qrow0 = blockIdx.x * 8;
    const int h = blockIdx.y;
    const int t = threadIdx.x;

    __shared__ __align__(16) float sc[8 * SEQ];
    __shared__ __align__(16) float red[2048];
    __shared__ __align__(16) float rtmp[256];
    __shared__ float linv[8];

    // scores
    {
        const int kg = t >> 3, sub = t & 7;
        float q[8][8];
        const float* qb = Q + (size_t)qrow0 * DIM + h * HD + sub * 8;
#pragma unroll
        for (int r = 0; r < 8; ++r) {
            float4 a = *(const float4*)(qb + (size_t)r * DIM);
            float4 b = *(const float4*)(qb + (size_t)r * DIM + 4);
            q[r][0] = a.x; q[r][1] = a.y; q[r][2] = a.z; q[r][3] = a.w;
            q[r][4] = b.x; q[r][5] = b.y; q[r][6] = b.z; q[r][7] = b.w;
        }
        for (int pass = 0; pass < 40; ++pass) {
            int kk = pass * 32 + kg;
            const float* kp = K + (size_t)kk * DIM + h * HD + sub * 8;
            float4 k0 = *(const float4*)kp;
            float4 k1 = *(const float4*)(kp + 4);
            float d[8];
#pragma unroll
            for (int r = 0; r < 8; ++r) {
                d[r] = q[r][0] * k0.x + q[r][1] * k0.y + q[r][2] * k0.z + q[r][3] * k0.w
                     + q[r][4] * k1.x + q[r][5] * k1.y + q[r][6] * k1.z + q[r][7] * k1.w;
            }
#pragma unroll
            for (int r = 0; r < 8; ++r) {
                d[r] += __shfl_xor(d[r], 1);
                d[r] += __shfl_xor(d[r], 2);
                d[r] += __shfl_xor(d[r], 4);
            }
            if (sub == 0) {
#pragma unroll
                for (int r = 0; r < 8; ++r) sc[r * SEQ + kk] = d[r] * 0.125f;
            }
        }
    }
    __syncthreads();

    // softmax
    {
        const int r = t >> 5, li = t & 31;
        float lm = -1e30f;
        for (int kk = li; kk < SEQ; kk += 32) lm = fmaxf(lm, sc[r * SEQ + kk]);
        rtmp[t] = lm;
        __syncthreads();
#pragma unroll
        for (int s = 16; s > 0; s >>= 1) {
            if (li < s) rtmp[t] = fmaxf(rtmp[t], rtmp[t + s]);
            __syncthreads();
        }
        float gmax = rtmp[(t >> 5) << 5];
        __syncthreads();
        float lsum = 0.0f;
        for (int kk = li; kk < SEQ; kk += 32) {
            float p = __expf(sc[r * SEQ + kk] - gmax);
            sc[r * SEQ + kk] = p;
            lsum += p;
        }
        rtmp[t] = lsum;
        __syncthreads();
#pragma unroll
        for (int s = 16; s > 0; s >>= 1) {
            if (li < s) rtmp[t] += rtmp[t + s];
            __syncthreads();
        }
        if (li == 0) linv[r] = 1.0f / rtmp[t];
    }
    __syncthreads();

    // PV
    {
        const int dg = t & 7, part = t >> 3;
        float acc[8][8];
#pragma unroll
        for (int r = 0; r < 8; ++r)
#pragma unroll
            for (int j = 0; j < 8; ++j) acc[r][j] = 0.0f;
        for (int kk = part * 40; kk < part * 40 + 40; ++kk) {
            const float* vp = V + (size_t)kk * DIM + h * HD + dg * 8;
            float4 v0 = *(const float4*)vp;
            float4 v1 = *(const float4*)(vp + 4);
#pragma unroll
            for (int r = 0; r < 8; ++r) {
                float p = sc[r * SEQ + kk];
                acc[r][0] += p * v0.x; acc[r][1] += p * v0.y;
                acc[r][2] += p * v0.z; acc[r][3] += p * v0.w;
                acc[r][4] += p * v1.x; acc[r][5] += p * v1.y;
                acc[r][6] += p * v1.z; acc[r][7] += p * v1.w;
            }
        }
        for (int r = 0; r < 8; ++r) {
#pragma unroll
            for (int j = 0; j < 8; ++j) red[part * 64 + dg * 8 + j] = acc[r][j];
            __syncthreads();
            if (t < 64) {
                float s = 0.0f;
#pragma unroll
                for (int p2 = 0; p2 < 32; ++p2) s += red[p2 * 64 + t];
                O[(size_t)(qrow0 + r) * DIM + h * HD + t] = s * linv[r];
            }
            __syncthreads();
        }
    }
}

__global__ __launch_bounds__(256) void add_f32(
    const float* __restrict__ a, const float* __restrict__ b,
    float* __restrict__ o, int n)
{
    int i = blockIdx.x * 256 + threadIdx.x;
    if (i < n) o[i] = a[i] + b[i];
}

// ---------------------------------------------------------------------------
extern "C" void kernel_launch(void* const* d_in, const int* in_sizes, int n_in,
                              void* d_out, int out_size, void* d_ws, size_t ws_size,
                              hipStream_t stream) {
    (void)in_sizes; (void)n_in; (void)out_size; (void)ws_size;
    const void* hs   = d_in[0];
    const void* ehs  = d_in[1];
    const void* hsc  = d_in[2];
    const void* ehsc = d_in[3];
    const void* i2q  = d_in[4];
    const void* pe   = d_in[5];
#define W_(i) ((const void*)d_in[i])

    const size_t SD = (size_t)SEQ * DIM;
    const size_t ID = (size_t)IMG * DIM;
    int*   flag = (int*)d_ws;
    float* fb = (float*)((char*)d_ws + 256);
    float* q1 = fb;            // SD  (qa, then qc, then oX)
    float* k1 = q1 + SD;       // SD  (ka, then kc)
    float* v1 = k1 + SD;       // SD  (va, then vc)
    float* oA = v1 + SD;       // SD  (attnA out; first ID becomes hsum in place)
    float* oC = oA + SD;       // SD
    float* qx = oC + SD;       // ID  -> total 5*SD + ID floats = 45.6 MB

    dim3 blk(256);
    detect_dtype<<<1, blk, 0, stream>>>(hs, flag);

    auto G1 = [&](const void* X, int iw, float* Y, int M) {
        gemm_in_f32out<<<dim3(DIM / 64, M / 64), blk, 0, stream>>>(X, W_(iw), W_(iw + 1), Y, flag);
    };
    // stream A qkv
    G1(hs, 6, q1, IMG);   G1(ehs, 12, q1 + ID, TXT);
    G1(hs, 8, k1, IMG);   G1(ehs, 14, k1 + ID, TXT);
    G1(hs, 10, v1, IMG);  G1(ehs, 16, v1 + ID, TXT);
    attn_f32<<<dim3(SEQ / 8, NH), blk, 0, stream>>>(q1, k1, v1, oA);

    // stream C qkv (reuse q1/k1/v1 — attnA done)
    G1(hsc, 22, q1, IMG); G1(ehsc, 28, q1 + ID, TXT);
    G1(hsc, 24, k1, IMG); G1(ehsc, 30, k1 + ID, TXT);
    G1(hsc, 26, v1, IMG); G1(ehsc, 32, v1 + ID, TXT);

    rope_f32_inplace<<<(SEQ * 768 + 255) / 256, blk, 0, stream>>>(q1, pe, flag, SEQ);
    rope_f32_inplace<<<(SEQ * 768 + 255) / 256, blk, 0, stream>>>(k1, pe, flag, SEQ);
    rope_in_to_f32<<<(IMG * 768 + 255) / 256, blk, 0, stream>>>(i2q, pe, qx, flag, IMG);

    attn_f32<<<dim3(SEQ / 8, NH), blk, 0, stream>>>(q1, k1, v1, oC);
    // cross: q1 (qc) dead after attnC -> reuse as oX
    attn_f32<<<dim3(IMG / 8, NH), blk, 0, stream>>>(qx, k1, v1, q1);

    // hsum = oA[:ID] + cross, in place into oA
    add_f32<<<((int)ID + 255) / 256, blk, 0, stream>>>(oA, q1, oA, (int)ID);

    const long TD = (long)TXT * DIM;
    gemm_f32split_out<<<dim3(DIM / 64, IMG / 64), blk, 0, stream>>>(oA,      W_(18), W_(19), d_out, 0,                  flag);
    gemm_f32split_out<<<dim3(DIM / 64, TXT / 64), blk, 0, stream>>>(oA + ID, W_(20), W_(21), d_out, (long)ID,          flag);
    gemm_f32split_out<<<dim3(DIM / 64, IMG / 64), blk, 0, stream>>>(oC,      W_(34), W_(35), d_out, (long)ID + TD,     flag);
    gemm_f32split_out<<<dim3(DIM / 64, TXT / 64), blk, 0, stream>>>(oC + ID, W_(36), W_(37), d_out, 2L * (long)ID + TD, flag);
#undef W_
}

// Round 3
// 1524.706 us; speedup vs baseline: 1.3395x; 1.3395x over previous
//
#include <hip/hip_runtime.h>

#define DIM 1536
#define IMG 1024
#define TXT 256
#define SEQ 1280
#define NH 24
#define HD 64

typedef __attribute__((ext_vector_type(8))) short short8;
typedef __attribute__((ext_vector_type(4))) float f32x4;

__device__ __forceinline__ float bf2f(ushort u) {
    union { unsigned int i; float f; } v; v.i = ((unsigned int)u) << 16; return v.f;
}
__device__ __forceinline__ ushort f2bf(float f) {
    union { unsigned int i; float f; } v; v.f = f;
    unsigned int u = v.i;
    u += 0x7fffu + ((u >> 16) & 1u);
    return (ushort)(u >> 16);
}

// ---------------------------------------------------------------------------
// Input-dtype detector (flag=1 -> fp32 underneath, flag=0 -> bf16).
// ---------------------------------------------------------------------------
__global__ __launch_bounds__(256) void detect_dtype(const void* __restrict__ p,
                                                    int* __restrict__ flag)
{
    __shared__ int cnt;
    if (threadIdx.x == 0) cnt = 0;
    __syncthreads();
    const ushort* u = (const ushort*)p;
    int local = 0;
    for (int i = threadIdx.x; i < 2048; i += 256) {
        ushort v = u[2 * i];
        int e = (v >> 7) & 0xFF;
        if (e >= 0xC0) local++;
    }
    atomicAdd(&cnt, local);
    __syncthreads();
    if (threadIdx.x == 0) flag[0] = (cnt > 16) ? 1 : 0;
}

// ---------------------------------------------------------------------------
// GEMM 1: Y(f32,ws) = X @ W + bias  (X,W,bias bf16 or fp32 per flag)
// ---------------------------------------------------------------------------
__global__ __launch_bounds__(256) void gemm_in_f32out(
    const void* __restrict__ X, const void* __restrict__ W,
    const void* __restrict__ bias, float* __restrict__ Y,
    const int* __restrict__ dflag)
{
    __shared__ __align__(16) ushort As[64][40];
    __shared__ __align__(16) ushort Bs[64][40];   // [n][k]
    const int dt = dflag[0];
    const int n0 = blockIdx.x * 64, m0 = blockIdx.y * 64;
    const int t = threadIdx.x;
    const int wave = t >> 6, lane = t & 63;
    const int quad = lane >> 4, l16 = lane & 15;
    const int wm = (wave >> 1) * 32, wn = (wave & 1) * 32;

    f32x4 acc[2][2];
#pragma unroll
    for (int i = 0; i < 2; ++i)
#pragma unroll
        for (int j = 0; j < 2; ++j) acc[i][j] = (f32x4)(0.0f);

    const int ar = t >> 2, ac = (t & 3) << 3;
    const int bk = t >> 3, bn = (t & 7) << 3;

    for (int k0 = 0; k0 < DIM; k0 += 32) {
        const size_t xoff = (size_t)(m0 + ar) * DIM + k0 + ac;
        if (dt) {
            const float* xp = (const float*)X + xoff;
            float4 a = *(const float4*)xp;
            float4 b = *(const float4*)(xp + 4);
            ushort tmp[8] = {f2bf(a.x), f2bf(a.y), f2bf(a.z), f2bf(a.w),
                             f2bf(b.x), f2bf(b.y), f2bf(b.z), f2bf(b.w)};
            *(uint4*)&As[ar][ac] = *(uint4*)tmp;
        } else {
            *(uint4*)&As[ar][ac] = *(const uint4*)((const ushort*)X + xoff);
        }
        const size_t woff = (size_t)(k0 + bk) * DIM + n0 + bn;
        ushort tmp[8];
        if (dt) {
            const float* wp = (const float*)W + woff;
            float4 a = *(const float4*)wp;
            float4 b = *(const float4*)(wp + 4);
            tmp[0] = f2bf(a.x); tmp[1] = f2bf(a.y); tmp[2] = f2bf(a.z); tmp[3] = f2bf(a.w);
            tmp[4] = f2bf(b.x); tmp[5] = f2bf(b.y); tmp[6] = f2bf(b.z); tmp[7] = f2bf(b.w);
        } else {
            *(uint4*)tmp = *(const uint4*)((const ushort*)W + woff);
        }
#pragma unroll
        for (int j = 0; j < 8; ++j) Bs[bn + j][bk] = tmp[j];
        __syncthreads();

        short8 a[2], b[2];
#pragma unroll
        for (int i = 0; i < 2; ++i) a[i] = *(const short8*)&As[wm + i * 16 + l16][quad * 8];
#pragma unroll
        for (int i = 0; i < 2; ++i) b[i] = *(const short8*)&Bs[wn + i * 16 + l16][quad * 8];
#pragma unroll
        for (int i = 0; i < 2; ++i)
#pragma unroll
            for (int j = 0; j < 2; ++j)
                acc[i][j] = __builtin_amdgcn_mfma_f32_16x16x32_bf16(a[i], b[j], acc[i][j], 0, 0, 0);
        __syncthreads();
    }

#pragma unroll
    for (int i = 0; i < 2; ++i)
#pragma unroll
        for (int j = 0; j < 2; ++j) {
            const int col = n0 + wn + j * 16 + l16;
            const float bv = dt ? ((const float*)bias)[col] : bf2f(((const ushort*)bias)[col]);
#pragma unroll
            for (int r = 0; r < 4; ++r) {
                const int row = m0 + wm + i * 16 + quad * 4 + r;
                Y[(size_t)row * DIM + col] = acc[i][j][r] + bv;
            }
        }
}

// ---------------------------------------------------------------------------
// GEMM 2: out(dtype per flag) = X(f32 ws, hi/lo split) @ W + bias.
// ---------------------------------------------------------------------------
__global__ __launch_bounds__(256) void gemm_f32split_out(
    const float* __restrict__ X, const void* __restrict__ W,
    const void* __restrict__ bias, void* __restrict__ Yb, long elem_off,
    const int* __restrict__ dflag)
{
    __shared__ __align__(16) ushort Ah[64][40];
    __shared__ __align__(16) ushort Al[64][40];
    __shared__ __align__(16) ushort Bs[64][40];
    const int dt = dflag[0];
    const int n0 = blockIdx.x * 64, m0 = blockIdx.y * 64;
    const int t = threadIdx.x;
    const int wave = t >> 6, lane = t & 63;
    const int quad = lane >> 4, l16 = lane & 15;
    const int wm = (wave >> 1) * 32, wn = (wave & 1) * 32;

    f32x4 acc[2][2];
#pragma unroll
    for (int i = 0; i < 2; ++i)
#pragma unroll
        for (int j = 0; j < 2; ++j) acc[i][j] = (f32x4)(0.0f);

    const int ar = t >> 2, ac = (t & 3) << 3;
    const int bk = t >> 3, bn = (t & 7) << 3;

    for (int k0 = 0; k0 < DIM; k0 += 32) {
        const float* xp = X + (size_t)(m0 + ar) * DIM + k0 + ac;
        float4 x0 = *(const float4*)xp;
        float4 x1 = *(const float4*)(xp + 4);
        float xs[8] = {x0.x, x0.y, x0.z, x0.w, x1.x, x1.y, x1.z, x1.w};
        ushort hi[8], lo[8];
#pragma unroll
        for (int j = 0; j < 8; ++j) {
            hi[j] = f2bf(xs[j]);
            lo[j] = f2bf(xs[j] - bf2f(hi[j]));
        }
        *(uint4*)&Ah[ar][ac] = *(uint4*)hi;
        *(uint4*)&Al[ar][ac] = *(uint4*)lo;
        const size_t woff = (size_t)(k0 + bk) * DIM + n0 + bn;
        ushort tmp[8];
        if (dt) {
            const float* wp = (const float*)W + woff;
            float4 a = *(const float4*)wp;
            float4 b = *(const float4*)(wp + 4);
            tmp[0] = f2bf(a.x); tmp[1] = f2bf(a.y); tmp[2] = f2bf(a.z); tmp[3] = f2bf(a.w);
            tmp[4] = f2bf(b.x); tmp[5] = f2bf(b.y); tmp[6] = f2bf(b.z); tmp[7] = f2bf(b.w);
        } else {
            *(uint4*)tmp = *(const uint4*)((const ushort*)W + woff);
        }
#pragma unroll
        for (int j = 0; j < 8; ++j) Bs[bn + j][bk] = tmp[j];
        __syncthreads();

        short8 ah[2], al[2], b[2];
#pragma unroll
        for (int i = 0; i < 2; ++i) ah[i] = *(const short8*)&Ah[wm + i * 16 + l16][quad * 8];
#pragma unroll
        for (int i = 0; i < 2; ++i) al[i] = *(const short8*)&Al[wm + i * 16 + l16][quad * 8];
#pragma unroll
        for (int i = 0; i < 2; ++i) b[i] = *(const short8*)&Bs[wn + i * 16 + l16][quad * 8];
#pragma unroll
        for (int i = 0; i < 2; ++i)
#pragma unroll
            for (int j = 0; j < 2; ++j) {
                acc[i][j] = __builtin_amdgcn_mfma_f32_16x16x32_bf16(ah[i], b[j], acc[i][j], 0, 0, 0);
                acc[i][j] = __builtin_amdgcn_mfma_f32_16x16x32_bf16(al[i], b[j], acc[i][j], 0, 0, 0);
            }
        __syncthreads();
    }

#pragma unroll
    for (int i = 0; i < 2; ++i)
#pragma unroll
        for (int j = 0; j < 2; ++j) {
            const int col = n0 + wn + j * 16 + l16;
            const float bv = dt ? ((const float*)bias)[col] : bf2f(((const ushort*)bias)[col]);
#pragma unroll
            for (int r = 0; r < 4; ++r) {
                const int row = m0 + wm + i * 16 + quad * 4 + r;
                const size_t o = (size_t)elem_off + (size_t)row * DIM + col;
                const float val = acc[i][j][r] + bv;
                if (dt) ((float*)Yb)[o] = val;
                else    ((ushort*)Yb)[o] = f2bf(val);
            }
        }
}

// ---------------------------------------------------------------------------
// RoPE kernels. pe flat layout: s*128 + i*4 + {cos,-sin,sin,cos}.
// ---------------------------------------------------------------------------
__device__ __forceinline__ void pe_load(const void* pe, int dt, size_t off,
                                        float& c00, float& c01, float& c10, float& c11)
{
    if (dt) {
        float4 pv = *(const float4*)((const float*)pe + off);
        c00 = pv.x; c01 = pv.y; c10 = pv.z; c11 = pv.w;
    } else {
        const ushort* pp = (const ushort*)pe + off;
        c00 = bf2f(pp[0]); c01 = bf2f(pp[1]); c10 = bf2f(pp[2]); c11 = bf2f(pp[3]);
    }
}

__global__ __launch_bounds__(256) void rope_f32_inplace(
    float* __restrict__ buf, const void* __restrict__ pe,
    const int* __restrict__ dflag, int S)
{
    const int dt = dflag[0];
    int idx = blockIdx.x * 256 + threadIdx.x;
    if (idx >= S * 768) return;
    int s = idx / 768, p = idx - s * 768;
    int col = p << 1, i = p & 31;
    float* bp = buf + (size_t)s * DIM + col;
    float x0 = bp[0], x1 = bp[1];
    float c00, c01, c10, c11;
    pe_load(pe, dt, (size_t)s * 128 + i * 4, c00, c01, c10, c11);
    bp[0] = c00 * x0 + c01 * x1;
    bp[1] = c10 * x0 + c11 * x1;
}

__global__ __launch_bounds__(256) void rope_in_to_f32(
    const void* __restrict__ src, const void* __restrict__ pe,
    float* __restrict__ dst, const int* __restrict__ dflag, int S)
{
    const int dt = dflag[0];
    int idx = blockIdx.x * 256 + threadIdx.x;
    if (idx >= S * 768) return;
    int s = idx / 768, p = idx - s * 768;
    int col = p << 1, i = p & 31;
    float x0, x1;
    if (dt) {
        float2 xv = *(const float2*)((const float*)src + (size_t)s * DIM + col);
        x0 = xv.x; x1 = xv.y;
    } else {
        const ushort* sp = (const ushort*)src + (size_t)s * DIM + col;
        x0 = bf2f(sp[0]); x1 = bf2f(sp[1]);
    }
    float c00, c01, c10, c11;
    pe_load(pe, dt, (size_t)s * 128 + i * 4, c00, c01, c10, c11);
    float* dp = dst + (size_t)s * DIM + col;
    dp[0] = c00 * x0 + c01 * x1;
    dp[1] = c10 * x0 + c11 * x1;
}

// ---------------------------------------------------------------------------
// MFMA flash attention. fp32 in/out, bf16 hi/lo split internally (3-term
// products => fp32-fidelity). WG = 4 waves = 64 q rows of one head; kv tiles
// of 64. LDS planes [64][64] bf16 with granule-XOR swizzle (g ^ (row&7)) =>
// conflict-free staging writes and frag reads. Q planes are reused as P
// planes (wave-private rows => no extra barriers). 48 KB LDS.
// ---------------------------------------------------------------------------
__device__ __forceinline__ int swz(int row, int col) {
    return row * 64 + ((((col >> 3) ^ row) & 7) << 3) + (col & 7);
}
__device__ __forceinline__ short8 ldfrag(const ushort* plane, int row, int col) {
    return *(const short8*)&plane[swz(row, col)];
}

__global__ __launch_bounds__(256) void attn_mfma(
    const float* __restrict__ Q, const float* __restrict__ K,
    const float* __restrict__ V, float* __restrict__ O)
{
    __shared__ ushort Qh[4096], Ql[4096];   // reused as Ph/Pl after init
    __shared__ ushort Kh[4096], Kl[4096];
    __shared__ ushort Vh[4096], Vl[4096];   // transposed: [dim][kv]

    const int q0 = blockIdx.x * 64;
    const int h = blockIdx.y;
    const int t = threadIdx.x;
    const int wave = t >> 6, lane = t & 63;
    const int quad = lane >> 4, l16 = lane & 15;
    const int wq0 = wave * 16;

    // ---- stage Q (hi/lo), wave-local rows ----
    {
        const int row = t >> 2, c0 = (t & 3) << 4;
        const float* src = Q + (size_t)(q0 + row) * DIM + h * HD + c0;
        float x[16];
        *(float4*)&x[0]  = *(const float4*)(src);
        *(float4*)&x[4]  = *(const float4*)(src + 4);
        *(float4*)&x[8]  = *(const float4*)(src + 8);
        *(float4*)&x[12] = *(const float4*)(src + 12);
        ushort hi[16], lo[16];
#pragma unroll
        for (int i = 0; i < 16; ++i) {
            hi[i] = f2bf(x[i]);
            lo[i] = f2bf(x[i] - bf2f(hi[i]));
        }
        const int g0 = c0 >> 3;
        const int p0 = ((g0 ^ (row & 7)) & 7) << 3;
        const int p1 = (((g0 + 1) ^ (row & 7)) & 7) << 3;
        *(uint4*)&Qh[row * 64 + p0] = *(uint4*)&hi[0];
        *(uint4*)&Qh[row * 64 + p1] = *(uint4*)&hi[8];
        *(uint4*)&Ql[row * 64 + p0] = *(uint4*)&lo[0];
        *(uint4*)&Ql[row * 64 + p1] = *(uint4*)&lo[8];
    }
    // wave staged exactly its own 16 rows (t>>2 in [wq0, wq0+16)); no sync.

    short8 qfh[2], qfl[2];
#pragma unroll
    for (int c = 0; c < 2; ++c) {
        qfh[c] = ldfrag(Qh, wq0 + l16, c * 32 + quad * 8);
        qfl[c] = ldfrag(Ql, wq0 + l16, c * 32 + quad * 8);
    }

    float m_[4], l_[4];
#pragma unroll
    for (int r = 0; r < 4; ++r) { m_[r] = -3e38f; l_[r] = 0.0f; }
    f32x4 Oacc[4];
#pragma unroll
    for (int j = 0; j < 4; ++j) Oacc[j] = (f32x4)(0.0f);

    for (int kv0 = 0; kv0 < SEQ; kv0 += 64) {
        __syncthreads();   // previous tile's K/V consumers done
        // ---- stage K tile (row-major) ----
        {
            const int row = t >> 2, c0 = (t & 3) << 4;
            const float* src = K + (size_t)(kv0 + row) * DIM + h * HD + c0;
            float x[16];
            *(float4*)&x[0]  = *(const float4*)(src);
            *(float4*)&x[4]  = *(const float4*)(src + 4);
            *(float4*)&x[8]  = *(const float4*)(src + 8);
            *(float4*)&x[12] = *(const float4*)(src + 12);
            ushort hi[16], lo[16];
#pragma unroll
            for (int i = 0; i < 16; ++i) {
                hi[i] = f2bf(x[i]);
                lo[i] = f2bf(x[i] - bf2f(hi[i]));
            }
            const int g0 = c0 >> 3;
            const int p0 = ((g0 ^ (row & 7)) & 7) << 3;
            const int p1 = (((g0 + 1) ^ (row & 7)) & 7) << 3;
            *(uint4*)&Kh[row * 64 + p0] = *(uint4*)&hi[0];
            *(uint4*)&Kh[row * 64 + p1] = *(uint4*)&hi[8];
            *(uint4*)&Kl[row * 64 + p0] = *(uint4*)&lo[0];
            *(uint4*)&Kl[row * 64 + p1] = *(uint4*)&lo[8];
        }
        // ---- stage V tile transposed: Vt[dim][kv] ----
        {
            const int d = t & 63, rg = t >> 6;
            float x[16];
#pragma unroll
            for (int r = 0; r < 16; ++r)
                x[r] = V[(size_t)(kv0 + rg * 16 + r) * DIM + h * HD + d];
            ushort hi[16], lo[16];
#pragma unroll
            for (int i = 0; i < 16; ++i) {
                hi[i] = f2bf(x[i]);
                lo[i] = f2bf(x[i] - bf2f(hi[i]));
            }
            const int g0 = rg * 2;
            const int p0 = ((g0 ^ (d & 7)) & 7) << 3;
            const int p1 = (((g0 + 1) ^ (d & 7)) & 7) << 3;
            *(uint4*)&Vh[d * 64 + p0] = *(uint4*)&hi[0];
            *(uint4*)&Vh[d * 64 + p1] = *(uint4*)&hi[8];
            *(uint4*)&Vl[d * 64 + p0] = *(uint4*)&lo[0];
            *(uint4*)&Vl[d * 64 + p1] = *(uint4*)&lo[8];
        }
        __syncthreads();

        // ---- S = Q K^T (3-term split) ----
        f32x4 S[4];
#pragma unroll
        for (int j = 0; j < 4; ++j) S[j] = (f32x4)(0.0f);
#pragma unroll
        for (int c = 0; c < 2; ++c) {
#pragma unroll
            for (int j = 0; j < 4; ++j) {
                short8 bh = ldfrag(Kh, j * 16 + l16, c * 32 + quad * 8);
                short8 bl = ldfrag(Kl, j * 16 + l16, c * 32 + quad * 8);
                S[j] = __builtin_amdgcn_mfma_f32_16x16x32_bf16(qfh[c], bh, S[j], 0, 0, 0);
                S[j] = __builtin_amdgcn_mfma_f32_16x16x32_bf16(qfl[c], bh, S[j], 0, 0, 0);
                S[j] = __builtin_amdgcn_mfma_f32_16x16x32_bf16(qfh[c], bl, S[j], 0, 0, 0);
            }
        }
#pragma unroll
        for (int j = 0; j < 4; ++j)
#pragma unroll
            for (int r = 0; r < 4; ++r) S[j][r] *= 0.125f;

        // ---- online softmax (rows = quad*4+r, reduce across l16 lanes) ----
        float alpha[4];
#pragma unroll
        for (int r = 0; r < 4; ++r) {
            float mx = fmaxf(fmaxf(S[0][r], S[1][r]), fmaxf(S[2][r], S[3][r]));
            mx = fmaxf(mx, __shfl_xor(mx, 1));
            mx = fmaxf(mx, __shfl_xor(mx, 2));
            mx = fmaxf(mx, __shfl_xor(mx, 4));
            mx = fmaxf(mx, __shfl_xor(mx, 8));
            float mn = fmaxf(m_[r], mx);
            alpha[r] = __expf(m_[r] - mn);
            m_[r] = mn;
            float rs = 0.0f;
#pragma unroll
            for (int j = 0; j < 4; ++j) {
                float p = __expf(S[j][r] - mn);
                S[j][r] = p;
                rs += p;
            }
            rs += __shfl_xor(rs, 1);
            rs += __shfl_xor(rs, 2);
            rs += __shfl_xor(rs, 4);
            rs += __shfl_xor(rs, 8);
            l_[r] = l_[r] * alpha[r] + rs;
        }
#pragma unroll
        for (int j = 0; j < 4; ++j)
#pragma unroll
            for (int r = 0; r < 4; ++r) Oacc[j][r] *= alpha[r];

        // ---- write P (hi/lo) into reused Q planes (wave-private rows) ----
        {
            const int prow = wq0 + quad * 4;
#pragma unroll
            for (int j = 0; j < 4; ++j)
#pragma unroll
                for (int r = 0; r < 4; ++r) {
                    float p = S[j][r];
                    ushort ph = f2bf(p);
                    ushort pl = f2bf(p - bf2f(ph));
                    int idx = swz(prow + r, j * 16 + l16);
                    Qh[idx] = ph;
                    Ql[idx] = pl;
                }
        }
        // within-wave LDS write->read: lgkmcnt ordering, no barrier needed

        // ---- O += P V (3-term split) ----
#pragma unroll
        for (int c = 0; c < 2; ++c) {
            short8 pah = ldfrag(Qh, wq0 + l16, c * 32 + quad * 8);
            short8 pal = ldfrag(Ql, wq0 + l16, c * 32 + quad * 8);
#pragma unroll
            for (int jn = 0; jn < 4; ++jn) {
                short8 vbh = ldfrag(Vh, jn * 16 + l16, c * 32 + quad * 8);
                short8 vbl = ldfrag(Vl, jn * 16 + l16, c * 32 + quad * 8);
                Oacc[jn] = __builtin_amdgcn_mfma_f32_16x16x32_bf16(pah, vbh, Oacc[jn], 0, 0, 0);
                Oacc[jn] = __builtin_amdgcn_mfma_f32_16x16x32_bf16(pal, vbh, Oacc[jn], 0, 0, 0);
                Oacc[jn] = __builtin_amdgcn_mfma_f32_16x16x32_bf16(pah, vbl, Oacc[jn], 0, 0, 0);
            }
        }
    }

    // ---- epilogue ----
    float inv[4];
#pragma unroll
    for (int r = 0; r < 4; ++r) inv[r] = 1.0f / l_[r];
#pragma unroll
    for (int jn = 0; jn < 4; ++jn)
#pragma unroll
        for (int r = 0; r < 4; ++r) {
            const int row = q0 + wq0 + quad * 4 + r;
            O[(size_t)row * DIM + h * HD + jn * 16 + l16] = Oacc[jn][r] * inv[r];
        }
}

__global__ __launch_bounds__(256) void add_f32(
    const float* __restrict__ a, const float* __restrict__ b,
    float* __restrict__ o, int n)
{
    int i = blockIdx.x * 256 + threadIdx.x;
    if (i < n) o[i] = a[i] + b[i];
}

// ---------------------------------------------------------------------------
extern "C" void kernel_launch(void* const* d_in, const int* in_sizes, int n_in,
                              void* d_out, int out_size, void* d_ws, size_t ws_size,
                              hipStream_t stream) {
    (void)in_sizes; (void)n_in; (void)out_size; (void)ws_size;
    const void* hs   = d_in[0];
    const void* ehs  = d_in[1];
    const void* hsc  = d_in[2];
    const void* ehsc = d_in[3];
    const void* i2q  = d_in[4];
    const void* pe   = d_in[5];
#define W_(i) ((const void*)d_in[i])

    const size_t SD = (size_t)SEQ * DIM;
    const size_t ID = (size_t)IMG * DIM;
    int*   flag = (int*)d_ws;
    float* fb = (float*)((char*)d_ws + 256);
    float* q1 = fb;            // SD  (qa, then qc, then oX)
    float* k1 = q1 + SD;       // SD  (ka, then kc)
    float* v1 = k1 + SD;       // SD  (va, then vc)
    float* oA = v1 + SD;       // SD  (attnA out; first ID becomes hsum in place)
    float* oC = oA + SD;       // SD
    float* qx = oC + SD;       // ID

    dim3 blk(256);
    detect_dtype<<<1, blk, 0, stream>>>(hs, flag);

    auto G1 = [&](const void* X, int iw, float* Y, int M) {
        gemm_in_f32out<<<dim3(DIM / 64, M / 64), blk, 0, stream>>>(X, W_(iw), W_(iw + 1), Y, flag);
    };
    // stream A qkv
    G1(hs, 6, q1, IMG);   G1(ehs, 12, q1 + ID, TXT);
    G1(hs, 8, k1, IMG);   G1(ehs, 14, k1 + ID, TXT);
    G1(hs, 10, v1, IMG);  G1(ehs, 16, v1 + ID, TXT);
    attn_mfma<<<dim3(SEQ / 64, NH), blk, 0, stream>>>(q1, k1, v1, oA);

    // stream C qkv (reuse q1/k1/v1 — attnA done)
    G1(hsc, 22, q1, IMG); G1(ehsc, 28, q1 + ID, TXT);
    G1(hsc, 24, k1, IMG); G1(ehsc, 30, k1 + ID, TXT);
    G1(hsc, 26, v1, IMG); G1(ehsc, 32, v1 + ID, TXT);

    rope_f32_inplace<<<(SEQ * 768 + 255) / 256, blk, 0, stream>>>(q1, pe, flag, SEQ);
    rope_f32_inplace<<<(SEQ * 768 + 255) / 256, blk, 0, stream>>>(k1, pe, flag, SEQ);
    rope_in_to_f32<<<(IMG * 768 + 255) / 256, blk, 0, stream>>>(i2q, pe, qx, flag, IMG);

    attn_mfma<<<dim3(SEQ / 64, NH), blk, 0, stream>>>(q1, k1, v1, oC);
    // cross: q1 (qc) dead after attnC -> reuse as oX
    attn_mfma<<<dim3(IMG / 64, NH), blk, 0, stream>>>(qx, k1, v1, q1);

    // hsum = oA[:ID] + cross, in place into oA
    add_f32<<<((int)ID + 255) / 256, blk, 0, stream>>>(oA, q1, oA, (int)ID);

    const long TD = (long)TXT * DIM;
    gemm_f32split_out<<<dim3(DIM / 64, IMG / 64), blk, 0, stream>>>(oA,      W_(18), W_(19), d_out, 0,                   flag);
    gemm_f32split_out<<<dim3(DIM / 64, TXT / 64), blk, 0, stream>>>(oA + ID, W_(20), W_(21), d_out, (long)ID,           flag);
    gemm_f32split_out<<<dim3(DIM / 64, IMG / 64), blk, 0, stream>>>(oC,      W_(34), W_(35), d_out, (long)ID + TD,      flag);
    gemm_f32split_out<<<dim3(DIM / 64, TXT / 64), blk, 0, stream>>>(oC + ID, W_(36), W_(37), d_out, 2L * (long)ID + TD, flag);
#undef W_
}

// Round 4
// 1265.788 us; speedup vs baseline: 1.6135x; 1.2046x over previous
//
#include <hip/hip_runtime.h>

#define DIM 1536
#define IMG 1024
#define TXT 256
#define SEQ 1280
#define NH 24
#define HD 64

typedef __attribute__((ext_vector_type(8))) short short8;
typedef __attribute__((ext_vector_type(4))) float f32x4;

__device__ __forceinline__ float bf2f(ushort u) {
    union { unsigned int i; float f; } v; v.i = ((unsigned int)u) << 16; return v.f;
}
__device__ __forceinline__ ushort f2bf(float f) {
    union { unsigned int i; float f; } v; v.f = f;
    unsigned int u = v.i;
    u += 0x7fffu + ((u >> 16) & 1u);
    return (ushort)(u >> 16);
}

// ---------------------------------------------------------------------------
// Input-dtype detector (flag=1 -> fp32 underneath, flag=0 -> bf16).
// ---------------------------------------------------------------------------
__global__ __launch_bounds__(256) void detect_dtype(const void* __restrict__ p,
                                                    int* __restrict__ flag)
{
    __shared__ int cnt;
    if (threadIdx.x == 0) cnt = 0;
    __syncthreads();
    const ushort* u = (const ushort*)p;
    int local = 0;
    for (int i = threadIdx.x; i < 2048; i += 256) {
        ushort v = u[2 * i];
        int e = (v >> 7) & 0xFF;
        if (e >= 0xC0) local++;
    }
    atomicAdd(&cnt, local);
    __syncthreads();
    if (threadIdx.x == 0) flag[0] = (cnt > 16) ? 1 : 0;
}

// ---------------------------------------------------------------------------
// Fused QKV GEMM: Yw(f32) = X @ Ww + bw for w in {q,k,v}. 128x128 tile,
// BK=32, 4 waves each 64x64 (4x4 MFMA 16x16x32). blockIdx.x in [0,36):
// w = bx/12, n0 = (bx%12)*128.
// ---------------------------------------------------------------------------
__global__ __launch_bounds__(256) void gemm_qkv_fused(
    const void* __restrict__ X,
    const void* __restrict__ Wq, const void* __restrict__ Wk, const void* __restrict__ Wv,
    const void* __restrict__ bq, const void* __restrict__ bk, const void* __restrict__ bv,
    float* __restrict__ Yq, float* __restrict__ Yk, float* __restrict__ Yv,
    const int* __restrict__ dflag)
{
    __shared__ __align__(16) ushort As[128][40];
    __shared__ __align__(16) ushort Bs[128][40];   // [n][k]
    const int dt = dflag[0];
    const int bx = blockIdx.x;
    const int w = bx / 12;
    const int n0 = (bx - w * 12) * 128;
    const int m0 = blockIdx.y * 128;
    const void* W = (w == 0) ? Wq : (w == 1) ? Wk : Wv;
    const void* bias = (w == 0) ? bq : (w == 1) ? bk : bv;
    float* Y = (w == 0) ? Yq : (w == 1) ? Yk : Yv;

    const int t = threadIdx.x;
    const int wave = t >> 6, lane = t & 63;
    const int quad = lane >> 4, l16 = lane & 15;
    const int wm = (wave >> 1) * 64, wn = (wave & 1) * 64;

    f32x4 acc[4][4];
#pragma unroll
    for (int i = 0; i < 4; ++i)
#pragma unroll
        for (int j = 0; j < 4; ++j) acc[i][j] = (f32x4)(0.0f);

    const int arow = t >> 1, ac16 = (t & 1) << 4;      // A: 128 rows x 32 k
    const int bn8 = (t & 15) << 3, bkk = (t >> 4) << 1; // B: 8 n x 2 k per thread

    for (int k0 = 0; k0 < DIM; k0 += 32) {
        // ---- stage A ----
        {
            const size_t off = (size_t)(m0 + arow) * DIM + k0 + ac16;
            if (dt) {
                const float* xp = (const float*)X + off;
                float4 a0 = *(const float4*)xp;
                float4 a1 = *(const float4*)(xp + 4);
                float4 a2 = *(const float4*)(xp + 8);
                float4 a3 = *(const float4*)(xp + 12);
                ushort tmp[16] = {f2bf(a0.x), f2bf(a0.y), f2bf(a0.z), f2bf(a0.w),
                                  f2bf(a1.x), f2bf(a1.y), f2bf(a1.z), f2bf(a1.w),
                                  f2bf(a2.x), f2bf(a2.y), f2bf(a2.z), f2bf(a2.w),
                                  f2bf(a3.x), f2bf(a3.y), f2bf(a3.z), f2bf(a3.w)};
                *(uint4*)&As[arow][ac16]     = *(uint4*)&tmp[0];
                *(uint4*)&As[arow][ac16 + 8] = *(uint4*)&tmp[8];
            } else {
                const ushort* xp = (const ushort*)X + off;
                *(uint4*)&As[arow][ac16]     = *(const uint4*)xp;
                *(uint4*)&As[arow][ac16 + 8] = *(const uint4*)(xp + 8);
            }
        }
        // ---- stage B transposed: Bs[n][k], write k-pairs as b32 ----
        {
            ushort t0[8], t1[8];
            const size_t off0 = (size_t)(k0 + bkk) * DIM + n0 + bn8;
            if (dt) {
                const float* w0 = (const float*)W + off0;
                const float* w1 = w0 + DIM;
                float4 a0 = *(const float4*)w0, a1 = *(const float4*)(w0 + 4);
                float4 b0 = *(const float4*)w1, b1 = *(const float4*)(w1 + 4);
                t0[0]=f2bf(a0.x); t0[1]=f2bf(a0.y); t0[2]=f2bf(a0.z); t0[3]=f2bf(a0.w);
                t0[4]=f2bf(a1.x); t0[5]=f2bf(a1.y); t0[6]=f2bf(a1.z); t0[7]=f2bf(a1.w);
                t1[0]=f2bf(b0.x); t1[1]=f2bf(b0.y); t1[2]=f2bf(b0.z); t1[3]=f2bf(b0.w);
                t1[4]=f2bf(b1.x); t1[5]=f2bf(b1.y); t1[6]=f2bf(b1.z); t1[7]=f2bf(b1.w);
            } else {
                const ushort* w0 = (const ushort*)W + off0;
                *(uint4*)t0 = *(const uint4*)w0;
                *(uint4*)t1 = *(const uint4*)(w0 + DIM);
            }
#pragma unroll
            for (int j = 0; j < 8; ++j) {
                unsigned int v = (unsigned int)t0[j] | ((unsigned int)t1[j] << 16);
                *(unsigned int*)&Bs[bn8 + j][bkk] = v;
            }
        }
        __syncthreads();

        short8 a[4], b[4];
#pragma unroll
        for (int i = 0; i < 4; ++i) a[i] = *(const short8*)&As[wm + i * 16 + l16][quad * 8];
#pragma unroll
        for (int j = 0; j < 4; ++j) b[j] = *(const short8*)&Bs[wn + j * 16 + l16][quad * 8];
#pragma unroll
        for (int i = 0; i < 4; ++i)
#pragma unroll
            for (int j = 0; j < 4; ++j)
                acc[i][j] = __builtin_amdgcn_mfma_f32_16x16x32_bf16(a[i], b[j], acc[i][j], 0, 0, 0);
        __syncthreads();
    }

#pragma unroll
    for (int j = 0; j < 4; ++j) {
        const int col = n0 + wn + j * 16 + l16;
        const float bv = dt ? ((const float*)bias)[col] : bf2f(((const ushort*)bias)[col]);
#pragma unroll
        for (int i = 0; i < 4; ++i)
#pragma unroll
            for (int r = 0; r < 4; ++r) {
                const int row = m0 + wm + i * 16 + quad * 4 + r;
                Y[(size_t)row * DIM + col] = acc[i][j][r] + bv;
            }
    }
}

// ---------------------------------------------------------------------------
// Output projection: out(dtype per flag) = X(f32, hi/lo split) @ W + bias.
// 128x128 tile, BK=32, 32 MFMA per wave per K-step.
// ---------------------------------------------------------------------------
__global__ __launch_bounds__(256) void gemm_f32split_out(
    const float* __restrict__ X, const void* __restrict__ W,
    const void* __restrict__ bias, void* __restrict__ Yb, long elem_off,
    const int* __restrict__ dflag)
{
    __shared__ __align__(16) ushort Ah[128][40];
    __shared__ __align__(16) ushort Al[128][40];
    __shared__ __align__(16) ushort Bs[128][40];
    const int dt = dflag[0];
    const int n0 = blockIdx.x * 128, m0 = blockIdx.y * 128;
    const int t = threadIdx.x;
    const int wave = t >> 6, lane = t & 63;
    const int quad = lane >> 4, l16 = lane & 15;
    const int wm = (wave >> 1) * 64, wn = (wave & 1) * 64;

    f32x4 acc[4][4];
#pragma unroll
    for (int i = 0; i < 4; ++i)
#pragma unroll
        for (int j = 0; j < 4; ++j) acc[i][j] = (f32x4)(0.0f);

    const int arow = t >> 1, ac16 = (t & 1) << 4;
    const int bn8 = (t & 15) << 3, bkk = (t >> 4) << 1;

    for (int k0 = 0; k0 < DIM; k0 += 32) {
        {
            const float* xp = X + (size_t)(m0 + arow) * DIM + k0 + ac16;
            float x[16];
            *(float4*)&x[0]  = *(const float4*)(xp);
            *(float4*)&x[4]  = *(const float4*)(xp + 4);
            *(float4*)&x[8]  = *(const float4*)(xp + 8);
            *(float4*)&x[12] = *(const float4*)(xp + 12);
            ushort hi[16], lo[16];
#pragma unroll
            for (int i = 0; i < 16; ++i) {
                hi[i] = f2bf(x[i]);
                lo[i] = f2bf(x[i] - bf2f(hi[i]));
            }
            *(uint4*)&Ah[arow][ac16]     = *(uint4*)&hi[0];
            *(uint4*)&Ah[arow][ac16 + 8] = *(uint4*)&hi[8];
            *(uint4*)&Al[arow][ac16]     = *(uint4*)&lo[0];
            *(uint4*)&Al[arow][ac16 + 8] = *(uint4*)&lo[8];
        }
        {
            ushort t0[8], t1[8];
            const size_t off0 = (size_t)(k0 + bkk) * DIM + n0 + bn8;
            if (dt) {
                const float* w0 = (const float*)W + off0;
                const float* w1 = w0 + DIM;
                float4 a0 = *(const float4*)w0, a1 = *(const float4*)(w0 + 4);
                float4 b0 = *(const float4*)w1, b1 = *(const float4*)(w1 + 4);
                t0[0]=f2bf(a0.x); t0[1]=f2bf(a0.y); t0[2]=f2bf(a0.z); t0[3]=f2bf(a0.w);
                t0[4]=f2bf(a1.x); t0[5]=f2bf(a1.y); t0[6]=f2bf(a1.z); t0[7]=f2bf(a1.w);
                t1[0]=f2bf(b0.x); t1[1]=f2bf(b0.y); t1[2]=f2bf(b0.z); t1[3]=f2bf(b0.w);
                t1[4]=f2bf(b1.x); t1[5]=f2bf(b1.y); t1[6]=f2bf(b1.z); t1[7]=f2bf(b1.w);
            } else {
                const ushort* w0 = (const ushort*)W + off0;
                *(uint4*)t0 = *(const uint4*)w0;
                *(uint4*)t1 = *(const uint4*)(w0 + DIM);
            }
#pragma unroll
            for (int j = 0; j < 8; ++j) {
                unsigned int v = (unsigned int)t0[j] | ((unsigned int)t1[j] << 16);
                *(unsigned int*)&Bs[bn8 + j][bkk] = v;
            }
        }
        __syncthreads();

        short8 b[4];
#pragma unroll
        for (int j = 0; j < 4; ++j) b[j] = *(const short8*)&Bs[wn + j * 16 + l16][quad * 8];
#pragma unroll
        for (int i = 0; i < 4; ++i) {
            short8 ah = *(const short8*)&Ah[wm + i * 16 + l16][quad * 8];
            short8 al = *(const short8*)&Al[wm + i * 16 + l16][quad * 8];
#pragma unroll
            for (int j = 0; j < 4; ++j) {
                acc[i][j] = __builtin_amdgcn_mfma_f32_16x16x32_bf16(ah, b[j], acc[i][j], 0, 0, 0);
                acc[i][j] = __builtin_amdgcn_mfma_f32_16x16x32_bf16(al, b[j], acc[i][j], 0, 0, 0);
            }
        }
        __syncthreads();
    }

#pragma unroll
    for (int j = 0; j < 4; ++j) {
        const int col = n0 + wn + j * 16 + l16;
        const float bv = dt ? ((const float*)bias)[col] : bf2f(((const ushort*)bias)[col]);
#pragma unroll
        for (int i = 0; i < 4; ++i)
#pragma unroll
            for (int r = 0; r < 4; ++r) {
                const int row = m0 + wm + i * 16 + quad * 4 + r;
                const size_t o = (size_t)elem_off + (size_t)row * DIM + col;
                const float val = acc[i][j][r] + bv;
                if (dt) ((float*)Yb)[o] = val;
                else    ((ushort*)Yb)[o] = f2bf(val);
            }
    }
}

// ---------------------------------------------------------------------------
// RoPE kernels. pe flat layout: s*128 + i*4 + {cos,-sin,sin,cos}.
// ---------------------------------------------------------------------------
__device__ __forceinline__ void pe_load(const void* pe, int dt, size_t off,
                                        float& c00, float& c01, float& c10, float& c11)
{
    if (dt) {
        float4 pv = *(const float4*)((const float*)pe + off);
        c00 = pv.x; c01 = pv.y; c10 = pv.z; c11 = pv.w;
    } else {
        const ushort* pp = (const ushort*)pe + off;
        c00 = bf2f(pp[0]); c01 = bf2f(pp[1]); c10 = bf2f(pp[2]); c11 = bf2f(pp[3]);
    }
}

__global__ __launch_bounds__(256) void rope_f32_inplace(
    float* __restrict__ buf, const void* __restrict__ pe,
    const int* __restrict__ dflag, int S)
{
    const int dt = dflag[0];
    int idx = blockIdx.x * 256 + threadIdx.x;
    if (idx >= S * 768) return;
    int s = idx / 768, p = idx - s * 768;
    int col = p << 1, i = p & 31;
    float* bp = buf + (size_t)s * DIM + col;
    float x0 = bp[0], x1 = bp[1];
    float c00, c01, c10, c11;
    pe_load(pe, dt, (size_t)s * 128 + i * 4, c00, c01, c10, c11);
    bp[0] = c00 * x0 + c01 * x1;
    bp[1] = c10 * x0 + c11 * x1;
}

__global__ __launch_bounds__(256) void rope_in_to_f32(
    const void* __restrict__ src, const void* __restrict__ pe,
    float* __restrict__ dst, const int* __restrict__ dflag, int S)
{
    const int dt = dflag[0];
    int idx = blockIdx.x * 256 + threadIdx.x;
    if (idx >= S * 768) return;
    int s = idx / 768, p = idx - s * 768;
    int col = p << 1, i = p & 31;
    float x0, x1;
    if (dt) {
        float2 xv = *(const float2*)((const float*)src + (size_t)s * DIM + col);
        x0 = xv.x; x1 = xv.y;
    } else {
        const ushort* sp = (const ushort*)src + (size_t)s * DIM + col;
        x0 = bf2f(sp[0]); x1 = bf2f(sp[1]);
    }
    float c00, c01, c10, c11;
    pe_load(pe, dt, (size_t)s * 128 + i * 4, c00, c01, c10, c11);
    float* dp = dst + (size_t)s * DIM + col;
    dp[0] = c00 * x0 + c01 * x1;
    dp[1] = c10 * x0 + c11 * x1;
}

// ---------------------------------------------------------------------------
// MFMA flash attention (unchanged from R3).
// ---------------------------------------------------------------------------
__device__ __forceinline__ int swz(int row, int col) {
    return row * 64 + ((((col >> 3) ^ row) & 7) << 3) + (col & 7);
}
__device__ __forceinline__ short8 ldfrag(const ushort* plane, int row, int col) {
    return *(const short8*)&plane[swz(row, col)];
}

__global__ __launch_bounds__(256) void attn_mfma(
    const float* __restrict__ Q, const float* __restrict__ K,
    const float* __restrict__ V, float* __restrict__ O)
{
    __shared__ ushort Qh[4096], Ql[4096];
    __shared__ ushort Kh[4096], Kl[4096];
    __shared__ ushort Vh[4096], Vl[4096];

    const int q0 = blockIdx.x * 64;
    const int h = blockIdx.y;
    const int t = threadIdx.x;
    const int wave = t >> 6, lane = t & 63;
    const int quad = lane >> 4, l16 = lane & 15;
    const int wq0 = wave * 16;

    {
        const int row = t >> 2, c0 = (t & 3) << 4;
        const float* src = Q + (size_t)(q0 + row) * DIM + h * HD + c0;
        float x[16];
        *(float4*)&x[0]  = *(const float4*)(src);
        *(float4*)&x[4]  = *(const float4*)(src + 4);
        *(float4*)&x[8]  = *(const float4*)(src + 8);
        *(float4*)&x[12] = *(const float4*)(src + 12);
        ushort hi[16], lo[16];
#pragma unroll
        for (int i = 0; i < 16; ++i) {
            hi[i] = f2bf(x[i]);
            lo[i] = f2bf(x[i] - bf2f(hi[i]));
        }
        const int g0 = c0 >> 3;
        const int p0 = ((g0 ^ (row & 7)) & 7) << 3;
        const int p1 = (((g0 + 1) ^ (row & 7)) & 7) << 3;
        *(uint4*)&Qh[row * 64 + p0] = *(uint4*)&hi[0];
        *(uint4*)&Qh[row * 64 + p1] = *(uint4*)&hi[8];
        *(uint4*)&Ql[row * 64 + p0] = *(uint4*)&lo[0];
        *(uint4*)&Ql[row * 64 + p1] = *(uint4*)&lo[8];
    }

    short8 qfh[2], qfl[2];
#pragma unroll
    for (int c = 0; c < 2; ++c) {
        qfh[c] = ldfrag(Qh, wq0 + l16, c * 32 + quad * 8);
        qfl[c] = ldfrag(Ql, wq0 + l16, c * 32 + quad * 8);
    }

    float m_[4], l_[4];
#pragma unroll
    for (int r = 0; r < 4; ++r) { m_[r] = -3e38f; l_[r] = 0.0f; }
    f32x4 Oacc[4];
#pragma unroll
    for (int j = 0; j < 4; ++j) Oacc[j] = (f32x4)(0.0f);

    for (int kv0 = 0; kv0 < SEQ; kv0 += 64) {
        __syncthreads();
        {
            const int row = t >> 2, c0 = (t & 3) << 4;
            const float* src = K + (size_t)(kv0 + row) * DIM + h * HD + c0;
            float x[16];
            *(float4*)&x[0]  = *(const float4*)(src);
            *(float4*)&x[4]  = *(const float4*)(src + 4);
            *(float4*)&x[8]  = *(const float4*)(src + 8);
            *(float4*)&x[12] = *(const float4*)(src + 12);
            ushort hi[16], lo[16];
#pragma unroll
            for (int i = 0; i < 16; ++i) {
                hi[i] = f2bf(x[i]);
                lo[i] = f2bf(x[i] - bf2f(hi[i]));
            }
            const int g0 = c0 >> 3;
            const int p0 = ((g0 ^ (row & 7)) & 7) << 3;
            const int p1 = (((g0 + 1) ^ (row & 7)) & 7) << 3;
            *(uint4*)&Kh[row * 64 + p0] = *(uint4*)&hi[0];
            *(uint4*)&Kh[row * 64 + p1] = *(uint4*)&hi[8];
            *(uint4*)&Kl[row * 64 + p0] = *(uint4*)&lo[0];
            *(uint4*)&Kl[row * 64 + p1] = *(uint4*)&lo[8];
        }
        {
            const int d = t & 63, rg = t >> 6;
            float x[16];
#pragma unroll
            for (int r = 0; r < 16; ++r)
                x[r] = V[(size_t)(kv0 + rg * 16 + r) * DIM + h * HD + d];
            ushort hi[16], lo[16];
#pragma unroll
            for (int i = 0; i < 16; ++i) {
                hi[i] = f2bf(x[i]);
                lo[i] = f2bf(x[i] - bf2f(hi[i]));
            }
            const int g0 = rg * 2;
            const int p0 = ((g0 ^ (d & 7)) & 7) << 3;
            const int p1 = (((g0 + 1) ^ (d & 7)) & 7) << 3;
            *(uint4*)&Vh[d * 64 + p0] = *(uint4*)&hi[0];
            *(uint4*)&Vh[d * 64 + p1] = *(uint4*)&hi[8];
            *(uint4*)&Vl[d * 64 + p0] = *(uint4*)&lo[0];
            *(uint4*)&Vl[d * 64 + p1] = *(uint4*)&lo[8];
        }
        __syncthreads();

        f32x4 S[4];
#pragma unroll
        for (int j = 0; j < 4; ++j) S[j] = (f32x4)(0.0f);
#pragma unroll
        for (int c = 0; c < 2; ++c) {
#pragma unroll
            for (int j = 0; j < 4; ++j) {
                short8 bh = ldfrag(Kh, j * 16 + l16, c * 32 + quad * 8);
                short8 bl = ldfrag(Kl, j * 16 + l16, c * 32 + quad * 8);
                S[j] = __builtin_amdgcn_mfma_f32_16x16x32_bf16(qfh[c], bh, S[j], 0, 0, 0);
                S[j] = __builtin_amdgcn_mfma_f32_16x16x32_bf16(qfl[c], bh, S[j], 0, 0, 0);
                S[j] = __builtin_amdgcn_mfma_f32_16x16x32_bf16(qfh[c], bl, S[j], 0, 0, 0);
            }
        }
#pragma unroll
        for (int j = 0; j < 4; ++j)
#pragma unroll
            for (int r = 0; r < 4; ++r) S[j][r] *= 0.125f;

        float alpha[4];
#pragma unroll
        for (int r = 0; r < 4; ++r) {
            float mx = fmaxf(fmaxf(S[0][r], S[1][r]), fmaxf(S[2][r], S[3][r]));
            mx = fmaxf(mx, __shfl_xor(mx, 1));
            mx = fmaxf(mx, __shfl_xor(mx, 2));
            mx = fmaxf(mx, __shfl_xor(mx, 4));
            mx = fmaxf(mx, __shfl_xor(mx, 8));
            float mn = fmaxf(m_[r], mx);
            alpha[r] = __expf(m_[r] - mn);
            m_[r] = mn;
            float rs = 0.0f;
#pragma unroll
            for (int j = 0; j < 4; ++j) {
                float p = __expf(S[j][r] - mn);
                S[j][r] = p;
                rs += p;
            }
            rs += __shfl_xor(rs, 1);
            rs += __shfl_xor(rs, 2);
            rs += __shfl_xor(rs, 4);
            rs += __shfl_xor(rs, 8);
            l_[r] = l_[r] * alpha[r] + rs;
        }
#pragma unroll
        for (int j = 0; j < 4; ++j)
#pragma unroll
            for (int r = 0; r < 4; ++r) Oacc[j][r] *= alpha[r];

        {
            const int prow = wq0 + quad * 4;
#pragma unroll
            for (int j = 0; j < 4; ++j)
#pragma unroll
                for (int r = 0; r < 4; ++r) {
                    float p = S[j][r];
                    ushort ph = f2bf(p);
                    ushort pl = f2bf(p - bf2f(ph));
                    int idx = swz(prow + r, j * 16 + l16);
                    Qh[idx] = ph;
                    Ql[idx] = pl;
                }
        }

#pragma unroll
        for (int c = 0; c < 2; ++c) {
            short8 pah = ldfrag(Qh, wq0 + l16, c * 32 + quad * 8);
            short8 pal = ldfrag(Ql, wq0 + l16, c * 32 + quad * 8);
#pragma unroll
            for (int jn = 0; jn < 4; ++jn) {
                short8 vbh = ldfrag(Vh, jn * 16 + l16, c * 32 + quad * 8);
                short8 vbl = ldfrag(Vl, jn * 16 + l16, c * 32 + quad * 8);
                Oacc[jn] = __builtin_amdgcn_mfma_f32_16x16x32_bf16(pah, vbh, Oacc[jn], 0, 0, 0);
                Oacc[jn] = __builtin_amdgcn_mfma_f32_16x16x32_bf16(pal, vbh, Oacc[jn], 0, 0, 0);
                Oacc[jn] = __builtin_amdgcn_mfma_f32_16x16x32_bf16(pah, vbl, Oacc[jn], 0, 0, 0);
            }
        }
    }

    float inv[4];
#pragma unroll
    for (int r = 0; r < 4; ++r) inv[r] = 1.0f / l_[r];
#pragma unroll
    for (int jn = 0; jn < 4; ++jn)
#pragma unroll
        for (int r = 0; r < 4; ++r) {
            const int row = q0 + wq0 + quad * 4 + r;
            O[(size_t)row * DIM + h * HD + jn * 16 + l16] = Oacc[jn][r] * inv[r];
        }
}

__global__ __launch_bounds__(256) void add_f32(
    const float* __restrict__ a, const float* __restrict__ b,
    float* __restrict__ o, int n)
{
    int i = blockIdx.x * 256 + threadIdx.x;
    if (i < n) o[i] = a[i] + b[i];
}

// ---------------------------------------------------------------------------
extern "C" void kernel_launch(void* const* d_in, const int* in_sizes, int n_in,
                              void* d_out, int out_size, void* d_ws, size_t ws_size,
                              hipStream_t stream) {
    (void)in_sizes; (void)n_in; (void)out_size; (void)ws_size;
    const void* hs   = d_in[0];
    const void* ehs  = d_in[1];
    const void* hsc  = d_in[2];
    const void* ehsc = d_in[3];
    const void* i2q  = d_in[4];
    const void* pe   = d_in[5];
#define W_(i) ((const void*)d_in[i])

    const size_t SD = (size_t)SEQ * DIM;
    const size_t ID = (size_t)IMG * DIM;
    int*   flag = (int*)d_ws;
    float* fb = (float*)((char*)d_ws + 256);
    float* q1 = fb;            // SD  (qa, then qc, then oX)
    float* k1 = q1 + SD;       // SD
    float* v1 = k1 + SD;       // SD
    float* oA = v1 + SD;       // SD
    float* oC = oA + SD;       // SD
    float* qx = oC + SD;       // ID

    dim3 blk(256);
    detect_dtype<<<1, blk, 0, stream>>>(hs, flag);

    auto QKV = [&](const void* X, int iq, int ik, int iv,
                   float* Yq, float* Yk, float* Yv, int M) {
        gemm_qkv_fused<<<dim3(36, M / 128), blk, 0, stream>>>(
            X, W_(iq), W_(ik), W_(iv), W_(iq + 1), W_(ik + 1), W_(iv + 1),
            Yq, Yk, Yv, flag);
    };

    // stream A qkv (fused)
    QKV(hs, 6, 8, 10, q1, k1, v1, IMG);
    QKV(ehs, 12, 14, 16, q1 + ID, k1 + ID, v1 + ID, TXT);
    attn_mfma<<<dim3(SEQ / 64, NH), blk, 0, stream>>>(q1, k1, v1, oA);

    // stream C qkv (fused; reuse q1/k1/v1 — attnA done)
    QKV(hsc, 22, 24, 26, q1, k1, v1, IMG);
    QKV(ehsc, 28, 30, 32, q1 + ID, k1 + ID, v1 + ID, TXT);

    rope_f32_inplace<<<(SEQ * 768 + 255) / 256, blk, 0, stream>>>(q1, pe, flag, SEQ);
    rope_f32_inplace<<<(SEQ * 768 + 255) / 256, blk, 0, stream>>>(k1, pe, flag, SEQ);
    rope_in_to_f32<<<(IMG * 768 + 255) / 256, blk, 0, stream>>>(i2q, pe, qx, flag, IMG);

    attn_mfma<<<dim3(SEQ / 64, NH), blk, 0, stream>>>(q1, k1, v1, oC);
    attn_mfma<<<dim3(IMG / 64, NH), blk, 0, stream>>>(qx, k1, v1, q1);

    add_f32<<<((int)ID + 255) / 256, blk, 0, stream>>>(oA, q1, oA, (int)ID);

    const long TD = (long)TXT * DIM;
    gemm_f32split_out<<<dim3(12, IMG / 128), blk, 0, stream>>>(oA,      W_(18), W_(19), d_out, 0,                   flag);
    gemm_f32split_out<<<dim3(12, TXT / 128), blk, 0, stream>>>(oA + ID, W_(20), W_(21), d_out, (long)ID,           flag);
    gemm_f32split_out<<<dim3(12, IMG / 128), blk, 0, stream>>>(oC,      W_(34), W_(35), d_out, (long)ID + TD,      flag);
    gemm_f32split_out<<<dim3(12, TXT / 128), blk, 0, stream>>>(oC + ID, W_(36), W_(37), d_out, 2L * (long)ID + TD, flag);
#undef W_
}

// Round 5
// 723.425 us; speedup vs baseline: 2.8232x; 1.7497x over previous
//
#include <hip/hip_runtime.h>

#define DIM 1536
#define IMG 1024
#define TXT 256
#define SEQ 1280
#define NH 24
#define HD 64

typedef __attribute__((ext_vector_type(8))) short short8;
typedef __attribute__((ext_vector_type(4))) float f32x4;

__device__ __forceinline__ float bf2f(ushort u) {
    union { unsigned int i; float f; } v; v.i = ((unsigned int)u) << 16; return v.f;
}
__device__ __forceinline__ ushort f2bf(float f) {
    union { unsigned int i; float f; } v; v.f = f;
    unsigned int u = v.i;
    u += 0x7fffu + ((u >> 16) & 1u);
    return (ushort)(u >> 16);
}

// ---------------------------------------------------------------------------
// Input-dtype detector (flag=1 -> fp32 underneath, flag=0 -> bf16).
// ---------------------------------------------------------------------------
__global__ __launch_bounds__(256) void detect_dtype(const void* __restrict__ p,
                                                    int* __restrict__ flag)
{
    __shared__ int cnt;
    if (threadIdx.x == 0) cnt = 0;
    __syncthreads();
    const ushort* u = (const ushort*)p;
    int local = 0;
    for (int i = threadIdx.x; i < 2048; i += 256) {
        ushort v = u[2 * i];
        int e = (v >> 7) & 0xFF;
        if (e >= 0xC0) local++;
    }
    atomicAdd(&cnt, local);
    __syncthreads();
    if (threadIdx.x == 0) flag[0] = (cnt > 16) ? 1 : 0;
}

// ---------------------------------------------------------------------------
// LDS swizzle for GEMM tiles, row stride 40 ushorts (32 data + 8 pad).
// A plane: pair-level XOR (pairs of 8-ushort granules stay contiguous for
// uint4 writes / b128 reads). B plane: granule-level XOR (b128 reads cover
// exactly one granule). Both give 2-way-or-free quarter-wave access.
// ---------------------------------------------------------------------------
#define LSTR 40

// ===========================================================================
// Fused QKV GEMM v2: dbuf + prefetch. M=1280 (img rows 0..1023 from Xi,
// txt rows 1024..1279 from Xt, weights selected per m-tile).
// grid.x = 36 (w=x/12 in {q,k,v}; n0=(x%12)*128), grid.y = 10 m-tiles.
// ===========================================================================
struct QKVP {
    const void* Xi; const void* Xt;
    const void* W[6];   // wq,wk,wv (img), waddq,waddk,waddv (txt)
    const void* B[6];
    float* Y[3];
};

__global__ __launch_bounds__(256) void gemm_qkv_v2(QKVP p, const int* __restrict__ dflag)
{
    __shared__ __align__(16) ushort As[2][128 * LSTR];
    __shared__ __align__(16) ushort Bs[2][128 * LSTR];
    const int dt = dflag[0];
    const int bx = blockIdx.x;
    const int wsel = bx / 12;
    const int n0 = (bx - wsel * 12) * 128;
    const int m0g = blockIdx.y * 128;
    const bool istxt = (m0g >= IMG);
    const int m0 = istxt ? (m0g - IMG) : m0g;
    const void* X  = istxt ? p.Xt : p.Xi;
    const void* Wp = p.W[wsel + (istxt ? 3 : 0)];
    const void* Bp = p.B[wsel + (istxt ? 3 : 0)];
    float* Y = p.Y[wsel];

    const int t = threadIdx.x;
    const int wave = t >> 6, lane = t & 63;
    const int quad = lane >> 4, l16 = lane & 15;
    const int wm = (wave >> 1) * 64, wn = (wave & 1) * 64;

    const int arow = t >> 1, apair = t & 1;
    const int bn8 = (t & 15) << 3, bkk = (t >> 4) << 1;
    const int aps = apair ^ ((arow >> 3) & 1);
    const int adst = arow * LSTR + aps * 16;
    const int bq = bkk >> 3, bo = bkk & 7;

    f32x4 acc[4][4];
#pragma unroll
    for (int i = 0; i < 4; ++i)
#pragma unroll
        for (int j = 0; j < 4; ++j) acc[i][j] = (f32x4)(0.0f);

    float4 raf[4]; uint4 rau[2];
    float4 rbf[4]; uint4 rbu[2];

    auto loadA = [&](int k0) {
        const size_t off = (size_t)(m0 + arow) * DIM + k0 + apair * 16;
        if (dt) {
            const float* xp = (const float*)X + off;
            raf[0] = *(const float4*)xp;       raf[1] = *(const float4*)(xp + 4);
            raf[2] = *(const float4*)(xp + 8); raf[3] = *(const float4*)(xp + 12);
        } else {
            const ushort* xp = (const ushort*)X + off;
            rau[0] = *(const uint4*)xp;
            rau[1] = *(const uint4*)(xp + 8);
        }
    };
    auto loadB = [&](int k0) {
        const size_t off = (size_t)(k0 + bkk) * DIM + n0 + bn8;
        if (dt) {
            const float* wp0 = (const float*)Wp + off;
            rbf[0] = *(const float4*)wp0;         rbf[1] = *(const float4*)(wp0 + 4);
            rbf[2] = *(const float4*)(wp0 + DIM); rbf[3] = *(const float4*)(wp0 + DIM + 4);
        } else {
            const ushort* wp0 = (const ushort*)Wp + off;
            rbu[0] = *(const uint4*)wp0;
            rbu[1] = *(const uint4*)(wp0 + DIM);
        }
    };
    auto storeA = [&](int buf) {
        ushort tmp[16];
        if (dt) {
            const float* xs = (const float*)raf;
#pragma unroll
            for (int i = 0; i < 16; ++i) tmp[i] = f2bf(xs[i]);
        } else {
            *(uint4*)&tmp[0] = rau[0];
            *(uint4*)&tmp[8] = rau[1];
        }
        *(uint4*)&As[buf][adst]     = *(uint4*)&tmp[0];
        *(uint4*)&As[buf][adst + 8] = *(uint4*)&tmp[8];
    };
    auto storeB = [&](int buf) {
        ushort t0[8], t1[8];
        if (dt) {
            const float* f = (const float*)rbf;
#pragma unroll
            for (int j = 0; j < 8; ++j) { t0[j] = f2bf(f[j]); t1[j] = f2bf(f[8 + j]); }
        } else {
            *(uint4*)t0 = rbu[0];
            *(uint4*)t1 = rbu[1];
        }
#pragma unroll
        for (int j = 0; j < 8; ++j) {
            const int rr = bn8 + j;
            const int col = (((bq ^ (rr >> 3)) & 3) << 3) + bo;
            *(unsigned int*)&Bs[buf][rr * LSTR + col] =
                (unsigned int)t0[j] | ((unsigned int)t1[j] << 16);
        }
    };

    loadA(0); loadB(0);
    storeA(0); storeB(0);
    __syncthreads();

    for (int k = 0; k < DIM / 32; ++k) {
        const int cur = k & 1;
        const bool hn = (k + 1) < DIM / 32;
        if (hn) { loadA((k + 1) * 32); loadB((k + 1) * 32); }

        short8 b[4];
#pragma unroll
        for (int j = 0; j < 4; ++j) {
            const int rr = wn + j * 16 + l16;
            const int col = (((quad ^ (rr >> 3)) & 3) << 3);
            b[j] = *(const short8*)&Bs[cur][rr * LSTR + col];
        }
#pragma unroll
        for (int i = 0; i < 4; ++i) {
            const int rr = wm + i * 16 + l16;
            const int ps = (quad >> 1) ^ ((rr >> 3) & 1);
            const int col = ps * 16 + (quad & 1) * 8;
            short8 a = *(const short8*)&As[cur][rr * LSTR + col];
#pragma unroll
            for (int j = 0; j < 4; ++j)
                acc[i][j] = __builtin_amdgcn_mfma_f32_16x16x32_bf16(a, b[j], acc[i][j], 0, 0, 0);
        }
        if (hn) { storeA(cur ^ 1); storeB(cur ^ 1); }
        __syncthreads();
    }

#pragma unroll
    for (int j = 0; j < 4; ++j) {
        const int col = n0 + wn + j * 16 + l16;
        const float bv = dt ? ((const float*)Bp)[col] : bf2f(((const ushort*)Bp)[col]);
#pragma unroll
        for (int i = 0; i < 4; ++i)
#pragma unroll
            for (int r = 0; r < 4; ++r) {
                const int row = m0g + wm + i * 16 + quad * 4 + r;
                Y[(size_t)row * DIM + col] = acc[i][j][r] + bv;
            }
    }
}

// ===========================================================================
// Merged output projections: X = 2560 contiguous f32 rows (oA 1280 + oC 1280),
// hi/lo split A, per-m-tile weight segment: [0,8)=a_out, [8,10)=a_addout,
// [10,18)=c_out, [18,20)=c_addout. Out rows map 1:1 to concatenated d_out.
// grid = (12, 20).
// ===========================================================================
struct OutP {
    const float* X;
    const void* W[4]; const void* B[4];
    void* out;
};

__global__ __launch_bounds__(256) void gemm_out_v2(OutP p, const int* __restrict__ dflag)
{
    __shared__ __align__(16) ushort Ah[2][128 * LSTR];
    __shared__ __align__(16) ushort Al[2][128 * LSTR];
    __shared__ __align__(16) ushort Bs[2][128 * LSTR];
    const int dt = dflag[0];
    const int n0 = blockIdx.x * 128;
    const int mt = blockIdx.y;
    const int seg = (mt < 8) ? 0 : (mt < 10) ? 1 : (mt < 18) ? 2 : 3;
    const void* Wp = p.W[seg];
    const void* Bp = p.B[seg];
    const int m0 = mt * 128;

    const int t = threadIdx.x;
    const int wave = t >> 6, lane = t & 63;
    const int quad = lane >> 4, l16 = lane & 15;
    const int wm = (wave >> 1) * 64, wn = (wave & 1) * 64;

    const int arow = t >> 1, apair = t & 1;
    const int bn8 = (t & 15) << 3, bkk = (t >> 4) << 1;
    const int aps = apair ^ ((arow >> 3) & 1);
    const int adst = arow * LSTR + aps * 16;
    const int bq = bkk >> 3, bo = bkk & 7;

    f32x4 acc[4][4];
#pragma unroll
    for (int i = 0; i < 4; ++i)
#pragma unroll
        for (int j = 0; j < 4; ++j) acc[i][j] = (f32x4)(0.0f);

    float4 raf[4];
    float4 rbf[4]; uint4 rbu[2];

    auto loadA = [&](int k0) {
        const float* xp = p.X + (size_t)(m0 + arow) * DIM + k0 + apair * 16;
        raf[0] = *(const float4*)xp;       raf[1] = *(const float4*)(xp + 4);
        raf[2] = *(const float4*)(xp + 8); raf[3] = *(const float4*)(xp + 12);
    };
    auto loadB = [&](int k0) {
        const size_t off = (size_t)(k0 + bkk) * DIM + n0 + bn8;
        if (dt) {
            const float* wp0 = (const float*)Wp + off;
            rbf[0] = *(const float4*)wp0;         rbf[1] = *(const float4*)(wp0 + 4);
            rbf[2] = *(const float4*)(wp0 + DIM); rbf[3] = *(const float4*)(wp0 + DIM + 4);
        } else {
            const ushort* wp0 = (const ushort*)Wp + off;
            rbu[0] = *(const uint4*)wp0;
            rbu[1] = *(const uint4*)(wp0 + DIM);
        }
    };
    auto storeA = [&](int buf) {
        ushort hi[16], lo[16];
        const float* xs = (const float*)raf;
#pragma unroll
        for (int i = 0; i < 16; ++i) {
            hi[i] = f2bf(xs[i]);
            lo[i] = f2bf(xs[i] - bf2f(hi[i]));
        }
        *(uint4*)&Ah[buf][adst]     = *(uint4*)&hi[0];
        *(uint4*)&Ah[buf][adst + 8] = *(uint4*)&hi[8];
        *(uint4*)&Al[buf][adst]     = *(uint4*)&lo[0];
        *(uint4*)&Al[buf][adst + 8] = *(uint4*)&lo[8];
    };
    auto storeB = [&](int buf) {
        ushort t0[8], t1[8];
        if (dt) {
            const float* f = (const float*)rbf;
#pragma unroll
            for (int j = 0; j < 8; ++j) { t0[j] = f2bf(f[j]); t1[j] = f2bf(f[8 + j]); }
        } else {
            *(uint4*)t0 = rbu[0];
            *(uint4*)t1 = rbu[1];
        }
#pragma unroll
        for (int j = 0; j < 8; ++j) {
            const int rr = bn8 + j;
            const int col = (((bq ^ (rr >> 3)) & 3) << 3) + bo;
            *(unsigned int*)&Bs[buf][rr * LSTR + col] =
                (unsigned int)t0[j] | ((unsigned int)t1[j] << 16);
        }
    };

    loadA(0); loadB(0);
    storeA(0); storeB(0);
    __syncthreads();

    for (int k = 0; k < DIM / 32; ++k) {
        const int cur = k & 1;
        const bool hn = (k + 1) < DIM / 32;
        if (hn) { loadA((k + 1) * 32); loadB((k + 1) * 32); }

        short8 b[4];
#pragma unroll
        for (int j = 0; j < 4; ++j) {
            const int rr = wn + j * 16 + l16;
            const int col = (((quad ^ (rr >> 3)) & 3) << 3);
            b[j] = *(const short8*)&Bs[cur][rr * LSTR + col];
        }
#pragma unroll
        for (int i = 0; i < 4; ++i) {
            const int rr = wm + i * 16 + l16;
            const int ps = (quad >> 1) ^ ((rr >> 3) & 1);
            const int col = ps * 16 + (quad & 1) * 8;
            short8 ah = *(const short8*)&Ah[cur][rr * LSTR + col];
            short8 al = *(const short8*)&Al[cur][rr * LSTR + col];
#pragma unroll
            for (int j = 0; j < 4; ++j) {
                acc[i][j] = __builtin_amdgcn_mfma_f32_16x16x32_bf16(ah, b[j], acc[i][j], 0, 0, 0);
                acc[i][j] = __builtin_amdgcn_mfma_f32_16x16x32_bf16(al, b[j], acc[i][j], 0, 0, 0);
            }
        }
        if (hn) { storeA(cur ^ 1); storeB(cur ^ 1); }
        __syncthreads();
    }

#pragma unroll
    for (int j = 0; j < 4; ++j) {
        const int col = n0 + wn + j * 16 + l16;
        const float bv = dt ? ((const float*)Bp)[col] : bf2f(((const ushort*)Bp)[col]);
#pragma unroll
        for (int i = 0; i < 4; ++i)
#pragma unroll
            for (int r = 0; r < 4; ++r) {
                const int grow = m0 + wm + i * 16 + quad * 4 + r;
                const size_t o = (size_t)grow * DIM + col;
                const float val = acc[i][j][r] + bv;
                if (dt) ((float*)p.out)[o] = val;
                else    ((ushort*)p.out)[o] = f2bf(val);
            }
    }
}

// ---------------------------------------------------------------------------
// RoPE kernels. pe flat layout: s*128 + i*4 + {cos,-sin,sin,cos}.
// ---------------------------------------------------------------------------
__device__ __forceinline__ void pe_load(const void* pe, int dt, size_t off,
                                        float& c00, float& c01, float& c10, float& c11)
{
    if (dt) {
        float4 pv = *(const float4*)((const float*)pe + off);
        c00 = pv.x; c01 = pv.y; c10 = pv.z; c11 = pv.w;
    } else {
        const ushort* pp = (const ushort*)pe + off;
        c00 = bf2f(pp[0]); c01 = bf2f(pp[1]); c10 = bf2f(pp[2]); c11 = bf2f(pp[3]);
    }
}

__global__ __launch_bounds__(256) void rope_f32_inplace(
    float* __restrict__ buf, const void* __restrict__ pe,
    const int* __restrict__ dflag, int S)
{
    const int dt = dflag[0];
    int idx = blockIdx.x * 256 + threadIdx.x;
    if (idx >= S * 768) return;
    int s = idx / 768, p = idx - s * 768;
    int col = p << 1, i = p & 31;
    float* bp = buf + (size_t)s * DIM + col;
    float x0 = bp[0], x1 = bp[1];
    float c00, c01, c10, c11;
    pe_load(pe, dt, (size_t)s * 128 + i * 4, c00, c01, c10, c11);
    bp[0] = c00 * x0 + c01 * x1;
    bp[1] = c10 * x0 + c11 * x1;
}

__global__ __launch_bounds__(256) void rope_in_to_f32(
    const void* __restrict__ src, const void* __restrict__ pe,
    float* __restrict__ dst, const int* __restrict__ dflag, int S)
{
    const int dt = dflag[0];
    int idx = blockIdx.x * 256 + threadIdx.x;
    if (idx >= S * 768) return;
    int s = idx / 768, p = idx - s * 768;
    int col = p << 1, i = p & 31;
    float x0, x1;
    if (dt) {
        float2 xv = *(const float2*)((const float*)src + (size_t)s * DIM + col);
        x0 = xv.x; x1 = xv.y;
    } else {
        const ushort* sp = (const ushort*)src + (size_t)s * DIM + col;
        x0 = bf2f(sp[0]); x1 = bf2f(sp[1]);
    }
    float c00, c01, c10, c11;
    pe_load(pe, dt, (size_t)s * 128 + i * 4, c00, c01, c10, c11);
    float* dp = dst + (size_t)s * DIM + col;
    dp[0] = c00 * x0 + c01 * x1;
    dp[1] = c10 * x0 + c11 * x1;
}

// ---------------------------------------------------------------------------
// MFMA flash attention (unchanged from R3; measured 0 bank conflicts).
// ---------------------------------------------------------------------------
__device__ __forceinline__ int swz(int row, int col) {
    return row * 64 + ((((col >> 3) ^ row) & 7) << 3) + (col & 7);
}
__device__ __forceinline__ short8 ldfrag(const ushort* plane, int row, int col) {
    return *(const short8*)&plane[swz(row, col)];
}

__global__ __launch_bounds__(256) void attn_mfma(
    const float* __restrict__ Q, const float* __restrict__ K,
    const float* __restrict__ V, float* __restrict__ O)
{
    __shared__ ushort Qh[4096], Ql[4096];
    __shared__ ushort Kh[4096], Kl[4096];
    __shared__ ushort Vh[4096], Vl[4096];

    const int q0 = blockIdx.x * 64;
    const int h = blockIdx.y;
    const int t = threadIdx.x;
    const int wave = t >> 6, lane = t & 63;
    const int quad = lane >> 4, l16 = lane & 15;
    const int wq0 = wave * 16;

    {
        const int row = t >> 2, c0 = (t & 3) << 4;
        const float* src = Q + (size_t)(q0 + row) * DIM + h * HD + c0;
        float x[16];
        *(float4*)&x[0]  = *(const float4*)(src);
        *(float4*)&x[4]  = *(const float4*)(src + 4);
        *(float4*)&x[8]  = *(const float4*)(src + 8);
        *(float4*)&x[12] = *(const float4*)(src + 12);
        ushort hi[16], lo[16];
#pragma unroll
        for (int i = 0; i < 16; ++i) {
            hi[i] = f2bf(x[i]);
            lo[i] = f2bf(x[i] - bf2f(hi[i]));
        }
        const int g0 = c0 >> 3;
        const int p0 = ((g0 ^ (row & 7)) & 7) << 3;
        const int p1 = (((g0 + 1) ^ (row & 7)) & 7) << 3;
        *(uint4*)&Qh[row * 64 + p0] = *(uint4*)&hi[0];
        *(uint4*)&Qh[row * 64 + p1] = *(uint4*)&hi[8];
        *(uint4*)&Ql[row * 64 + p0] = *(uint4*)&lo[0];
        *(uint4*)&Ql[row * 64 + p1] = *(uint4*)&lo[8];
    }

    short8 qfh[2], qfl[2];
#pragma unroll
    for (int c = 0; c < 2; ++c) {
        qfh[c] = ldfrag(Qh, wq0 + l16, c * 32 + quad * 8);
        qfl[c] = ldfrag(Ql, wq0 + l16, c * 32 + quad * 8);
    }

    float m_[4], l_[4];
#pragma unroll
    for (int r = 0; r < 4; ++r) { m_[r] = -3e38f; l_[r] = 0.0f; }
    f32x4 Oacc[4];
#pragma unroll
    for (int j = 0; j < 4; ++j) Oacc[j] = (f32x4)(0.0f);

    for (int kv0 = 0; kv0 < SEQ; kv0 += 64) {
        __syncthreads();
        {
            const int row = t >> 2, c0 = (t & 3) << 4;
            const float* src = K + (size_t)(kv0 + row) * DIM + h * HD + c0;
            float x[16];
            *(float4*)&x[0]  = *(const float4*)(src);
            *(float4*)&x[4]  = *(const float4*)(src + 4);
            *(float4*)&x[8]  = *(const float4*)(src + 8);
            *(float4*)&x[12] = *(const float4*)(src + 12);
            ushort hi[16], lo[16];
#pragma unroll
            for (int i = 0; i < 16; ++i) {
                hi[i] = f2bf(x[i]);
                lo[i] = f2bf(x[i] - bf2f(hi[i]));
            }
            const int g0 = c0 >> 3;
            const int p0 = ((g0 ^ (row & 7)) & 7) << 3;
            const int p1 = (((g0 + 1) ^ (row & 7)) & 7) << 3;
            *(uint4*)&Kh[row * 64 + p0] = *(uint4*)&hi[0];
            *(uint4*)&Kh[row * 64 + p1] = *(uint4*)&hi[8];
            *(uint4*)&Kl[row * 64 + p0] = *(uint4*)&lo[0];
            *(uint4*)&Kl[row * 64 + p1] = *(uint4*)&lo[8];
        }
        {
            const int d = t & 63, rg = t >> 6;
            float x[16];
#pragma unroll
            for (int r = 0; r < 16; ++r)
                x[r] = V[(size_t)(kv0 + rg * 16 + r) * DIM + h * HD + d];
            ushort hi[16], lo[16];
#pragma unroll
            for (int i = 0; i < 16; ++i) {
                hi[i] = f2bf(x[i]);
                lo[i] = f2bf(x[i] - bf2f(hi[i]));
            }
            const int g0 = rg * 2;
            const int p0 = ((g0 ^ (d & 7)) & 7) << 3;
            const int p1 = (((g0 + 1) ^ (d & 7)) & 7) << 3;
            *(uint4*)&Vh[d * 64 + p0] = *(uint4*)&hi[0];
            *(uint4*)&Vh[d * 64 + p1] = *(uint4*)&hi[8];
            *(uint4*)&Vl[d * 64 + p0] = *(uint4*)&lo[0];
            *(uint4*)&Vl[d * 64 + p1] = *(uint4*)&lo[8];
        }
        __syncthreads();

        f32x4 S[4];
#pragma unroll
        for (int j = 0; j < 4; ++j) S[j] = (f32x4)(0.0f);
#pragma unroll
        for (int c = 0; c < 2; ++c) {
#pragma unroll
            for (int j = 0; j < 4; ++j) {
                short8 bh = ldfrag(Kh, j * 16 + l16, c * 32 + quad * 8);
                short8 bl = ldfrag(Kl, j * 16 + l16, c * 32 + quad * 8);
                S[j] = __builtin_amdgcn_mfma_f32_16x16x32_bf16(qfh[c], bh, S[j], 0, 0, 0);
                S[j] = __builtin_amdgcn_mfma_f32_16x16x32_bf16(qfl[c], bh, S[j], 0, 0, 0);
                S[j] = __builtin_amdgcn_mfma_f32_16x16x32_bf16(qfh[c], bl, S[j], 0, 0, 0);
            }
        }
#pragma unroll
        for (int j = 0; j < 4; ++j)
#pragma unroll
            for (int r = 0; r < 4; ++r) S[j][r] *= 0.125f;

        float alpha[4];
#pragma unroll
        for (int r = 0; r < 4; ++r) {
            float mx = fmaxf(fmaxf(S[0][r], S[1][r]), fmaxf(S[2][r], S[3][r]));
            mx = fmaxf(mx, __shfl_xor(mx, 1));
            mx = fmaxf(mx, __shfl_xor(mx, 2));
            mx = fmaxf(mx, __shfl_xor(mx, 4));
            mx = fmaxf(mx, __shfl_xor(mx, 8));
            float mn = fmaxf(m_[r], mx);
            alpha[r] = __expf(m_[r] - mn);
            m_[r] = mn;
            float rs = 0.0f;
#pragma unroll
            for (int j = 0; j < 4; ++j) {
                float p = __expf(S[j][r] - mn);
                S[j][r] = p;
                rs += p;
            }
            rs += __shfl_xor(rs, 1);
            rs += __shfl_xor(rs, 2);
            rs += __shfl_xor(rs, 4);
            rs += __shfl_xor(rs, 8);
            l_[r] = l_[r] * alpha[r] + rs;
        }
#pragma unroll
        for (int j = 0; j < 4; ++j)
#pragma unroll
            for (int r = 0; r < 4; ++r) Oacc[j][r] *= alpha[r];

        {
            const int prow = wq0 + quad * 4;
#pragma unroll
            for (int j = 0; j < 4; ++j)
#pragma unroll
                for (int r = 0; r < 4; ++r) {
                    float p = S[j][r];
                    ushort ph = f2bf(p);
                    ushort pl = f2bf(p - bf2f(ph));
                    int idx = swz(prow + r, j * 16 + l16);
                    Qh[idx] = ph;
                    Ql[idx] = pl;
                }
        }

#pragma unroll
        for (int c = 0; c < 2; ++c) {
            short8 pah = ldfrag(Qh, wq0 + l16, c * 32 + quad * 8);
            short8 pal = ldfrag(Ql, wq0 + l16, c * 32 + quad * 8);
#pragma unroll
            for (int jn = 0; jn < 4; ++jn) {
                short8 vbh = ldfrag(Vh, jn * 16 + l16, c * 32 + quad * 8);
                short8 vbl = ldfrag(Vl, jn * 16 + l16, c * 32 + quad * 8);
                Oacc[jn] = __builtin_amdgcn_mfma_f32_16x16x32_bf16(pah, vbh, Oacc[jn], 0, 0, 0);
                Oacc[jn] = __builtin_amdgcn_mfma_f32_16x16x32_bf16(pal, vbh, Oacc[jn], 0, 0, 0);
                Oacc[jn] = __builtin_amdgcn_mfma_f32_16x16x32_bf16(pah, vbl, Oacc[jn], 0, 0, 0);
            }
        }
    }

    float inv[4];
#pragma unroll
    for (int r = 0; r < 4; ++r) inv[r] = 1.0f / l_[r];
#pragma unroll
    for (int jn = 0; jn < 4; ++jn)
#pragma unroll
        for (int r = 0; r < 4; ++r) {
            const int row = q0 + wq0 + quad * 4 + r;
            O[(size_t)row * DIM + h * HD + jn * 16 + l16] = Oacc[jn][r] * inv[r];
        }
}

__global__ __launch_bounds__(256) void add_f32(
    const float* __restrict__ a, const float* __restrict__ b,
    float* __restrict__ o, int n)
{
    int i = blockIdx.x * 256 + threadIdx.x;
    if (i < n) o[i] = a[i] + b[i];
}

// ---------------------------------------------------------------------------
extern "C" void kernel_launch(void* const* d_in, const int* in_sizes, int n_in,
                              void* d_out, int out_size, void* d_ws, size_t ws_size,
                              hipStream_t stream) {
    (void)in_sizes; (void)n_in; (void)out_size; (void)ws_size;
    const void* hs   = d_in[0];
    const void* ehs  = d_in[1];
    const void* hsc  = d_in[2];
    const void* ehsc = d_in[3];
    const void* i2q  = d_in[4];
    const void* pe   = d_in[5];
#define W_(i) ((const void*)d_in[i])

    const size_t SD = (size_t)SEQ * DIM;
    const size_t ID = (size_t)IMG * DIM;
    int*   flag = (int*)d_ws;
    float* fb = (float*)((char*)d_ws + 256);
    float* q1 = fb;            // SD
    float* k1 = q1 + SD;       // SD
    float* v1 = k1 + SD;       // SD
    float* oA = v1 + SD;       // SD  (rows 0..1279; becomes hsum[0:ID] in place)
    float* oC = oA + SD;       // SD  (MUST be oA+SD: out-proj X spans both)
    float* qx = oC + SD;       // ID

    dim3 blk(256);
    detect_dtype<<<1, blk, 0, stream>>>(hs, flag);

    auto QKV = [&](const void* Xi, const void* Xt, int iw0, int itw0) {
        QKVP p;
        p.Xi = Xi; p.Xt = Xt;
        for (int j = 0; j < 3; ++j) {
            p.W[j]     = W_(iw0 + 2 * j);  p.B[j]     = W_(iw0 + 2 * j + 1);
            p.W[3 + j] = W_(itw0 + 2 * j); p.B[3 + j] = W_(itw0 + 2 * j + 1);
        }
        p.Y[0] = q1; p.Y[1] = k1; p.Y[2] = v1;
        gemm_qkv_v2<<<dim3(36, 10), blk, 0, stream>>>(p, flag);
    };

    // stream A qkv (img+txt merged)
    QKV(hs, ehs, 6, 12);
    attn_mfma<<<dim3(SEQ / 64, NH), blk, 0, stream>>>(q1, k1, v1, oA);

    // stream C qkv
    QKV(hsc, ehsc, 22, 28);

    rope_f32_inplace<<<(SEQ * 768 + 255) / 256, blk, 0, stream>>>(q1, pe, flag, SEQ);
    rope_f32_inplace<<<(SEQ * 768 + 255) / 256, blk, 0, stream>>>(k1, pe, flag, SEQ);
    rope_in_to_f32<<<(IMG * 768 + 255) / 256, blk, 0, stream>>>(i2q, pe, qx, flag, IMG);

    attn_mfma<<<dim3(SEQ / 64, NH), blk, 0, stream>>>(q1, k1, v1, oC);
    attn_mfma<<<dim3(IMG / 64, NH), blk, 0, stream>>>(qx, k1, v1, q1);  // oX -> q1

    add_f32<<<((int)ID + 255) / 256, blk, 0, stream>>>(oA, q1, oA, (int)ID);

    OutP op;
    op.X = oA;
    op.W[0] = W_(18); op.B[0] = W_(19);
    op.W[1] = W_(20); op.B[1] = W_(21);
    op.W[2] = W_(34); op.B[2] = W_(35);
    op.W[3] = W_(36); op.B[3] = W_(37);
    op.out = d_out;
    gemm_out_v2<<<dim3(12, 20), blk, 0, stream>>>(op, flag);
#undef W_
}